// Round 10
// baseline (332.360 us; speedup 1.0000x reference)
//
#include <hip/hip_runtime.h>
#include <math.h>

#define EPSF 1e-7f

typedef unsigned short ushort_t;
typedef __attribute__((ext_vector_type(8))) short bf16x8;
typedef __attribute__((ext_vector_type(4))) float f32x4;

__device__ __forceinline__ float arcosh_f(float x) {
    x = fmaxf(x, 1.0f + EPSF);
    return logf(x + sqrtf(x * x - 1.0f));
}

__device__ __forceinline__ unsigned short f2bf(float f) {
    union { float f; unsigned u; } c; c.f = f;
    unsigned r = c.u + 0x7FFFu + ((c.u >> 16) & 1u);
    return (unsigned short)(r >> 16);
}
__device__ __forceinline__ float bf2f(unsigned short u) {
    union { unsigned u; float f; } c; c.u = ((unsigned)u) << 16;
    return c.f;
}

__device__ __forceinline__ float wredsum(float v) {
#pragma unroll
    for (int off = 32; off; off >>= 1) v += __shfl_xor(v, off, 64);
    return v;
}

__device__ __forceinline__ void llds16(const void* g, void* l) {
    __builtin_amdgcn_global_load_lds((const __attribute__((address_space(1))) unsigned int*)g,
                                     (__attribute__((address_space(3))) unsigned int*)l,
                                     16, 0, 0);
}

// ---------- K1: xt0 = log_map_zero(x) -> bf16. 4 rows per block (1 per wave) ----------
__global__ __launch_bounds__(256) void k_log0(const float* __restrict__ x,
                                              char* __restrict__ Abase, int N) {
    int wv = threadIdx.x >> 6, t = threadIdx.x & 63;
    int i = blockIdx.x * 4 + wv;
    if (i >= N) return;
    float2 v = *reinterpret_cast<const float2*>(x + (size_t)i * 128 + 2 * t);
    float y0 = __shfl(v.x, 0, 64);
    float a0 = (t == 0) ? 0.f : v.x;
    float s = wredsum(a0 * a0 + v.y * v.y);
    float dist = arcosh_f(y0 + EPSF);
    float scl = dist / sqrtf(s + EPSF);
    ushort2 o;
    o.x = f2bf(scl * a0);
    o.y = f2bf(scl * v.y);
    *reinterpret_cast<ushort2*>(Abase + (size_t)i * 512 + 256 + 4 * t) = o;
}

// ---------- bucket partition: 1024-node buckets ----------
__global__ __launch_bounds__(256) void k_c1(const int* __restrict__ edst,
                                            int* __restrict__ gcnt,
                                            int E, int NBKT, int EPB) {
    __shared__ int cnt[64];
    int blk = blockIdx.x, t = threadIdx.x;
    for (int i = t; i < NBKT; i += 256) cnt[i] = 0;
    __syncthreads();
    int lo = blk * EPB, hi = min(lo + EPB, E);
    for (int e = lo + t; e < hi; e += 256) atomicAdd(&cnt[edst[e] >> 10], 1);
    __syncthreads();
    for (int i = t; i < NBKT; i += 256) gcnt[blk * NBKT + i] = cnt[i];
}

__global__ __launch_bounds__(64) void k_c2(int* __restrict__ gcnt,
                                           int* __restrict__ bstart, int NBLK, int NBKT) {
    __shared__ int sh[10816];
    __shared__ int tot[64];
    __shared__ int bs[65];
    int t = threadIdx.x;
    int total = NBLK * NBKT;
    for (int i = t; i < total; i += 64) sh[i] = gcnt[i];
    __syncthreads();
    if (t < NBKT) {
        int run = 0;
        for (int blk = 0; blk < NBLK; ++blk) {
            int idx = blk * NBKT + t;
            int c = sh[idx]; sh[idx] = run; run += c;
        }
        tot[t] = run;
    }
    __syncthreads();
    if (t == 0) {
        int r = 0;
        for (int b = 0; b < NBKT; ++b) { bs[b] = r; r += tot[b]; }
        bs[NBKT] = r;
    }
    __syncthreads();
    if (t < NBKT) {
        bstart[t] = bs[t];
        if (t == 0) bstart[NBKT] = bs[NBKT];
    }
    for (int i = t; i < total; i += 64) gcnt[i] = sh[i] + bs[i % NBKT];
}

__global__ __launch_bounds__(256) void k_c3(const int* __restrict__ esrc,
                                            const int* __restrict__ edst,
                                            const int* __restrict__ gcnt,
                                            int2* __restrict__ ebuf,
                                            int E, int NBKT, int EPB) {
    __shared__ int cur[64];
    int blk = blockIdx.x, t = threadIdx.x;
    for (int i = t; i < NBKT; i += 256) cur[i] = 0;
    __syncthreads();
    int lo = blk * EPB, hi = min(lo + EPB, E);
    for (int e = lo + t; e < hi; e += 256) {
        int d = edst[e], s = esrc[e];
        int b = d >> 10;
        int r = atomicAdd(&cur[b], 1);
        ebuf[gcnt[blk * NBKT + b] + r] = make_int2(s, d);
    }
}

// ---------- c4: per-bucket exact CSR (L2-resident scatter) ----------
__global__ __launch_bounds__(256) void k_c4(const int2* __restrict__ ebuf,
                                            const int* __restrict__ bstart,
                                            int* __restrict__ row_ptr,
                                            int* __restrict__ srcl,
                                            int N, int NBKT, int E) {
    __shared__ int cnt[1024];
    __shared__ int cur[1024];
    __shared__ int sb[256];
    int b = blockIdx.x, t = threadIdx.x;
    int lo = b << 10;
    int nn = min(1024, N - lo);
    for (int i = t; i < 1024; i += 256) cnt[i] = 0;
    __syncthreads();
    int es = bstart[b], ee = bstart[b + 1];
    for (int e = es + t; e < ee; e += 256) atomicAdd(&cnt[ebuf[e].y - lo], 1);
    __syncthreads();
    int base = t * 4;
    int c0 = cnt[base], c1 = cnt[base + 1], c2 = cnt[base + 2], c3 = cnt[base + 3];
    int ts = c0 + c1 + c2 + c3;
    sb[t] = ts; __syncthreads();
    for (int st = 1; st < 256; st <<= 1) {
        int v = (t >= st) ? sb[t - st] : 0;
        __syncthreads();
        sb[t] += v;
        __syncthreads();
    }
    int run = es + sb[t] - ts;
    int rp[4];
    rp[0] = run; rp[1] = run + c0; rp[2] = rp[1] + c1; rp[3] = rp[2] + c2;
#pragma unroll
    for (int q = 0; q < 4; ++q) {
        cur[base + q] = rp[q];
        if (base + q < nn) row_ptr[lo + base + q] = rp[q];
    }
    if (b == NBKT - 1 && t == 0) row_ptr[N] = E;
    __syncthreads();
    for (int e = es + t; e < ee; e += 256) {
        int2 ed = ebuf[e];
        int r = atomicAdd(&cur[ed.y - lo], 1);
        srcl[r] = ed.x;
    }
}

// ---------- K3: agg (4-way unrolled gather, 1 row/wave, 4 rows/block) ----------
__global__ __launch_bounds__(256) void k_agg(const char* __restrict__ Abase,
                                             const int* __restrict__ row_ptr,
                                             const int* __restrict__ srcl,
                                             ushort_t* __restrict__ Ab, int N) {
    int wv = threadIdx.x >> 6, t = threadIdx.x & 63;
    int i = blockIdx.x * 4 + wv;
    if (i >= N) return;
    const char* base = Abase + 256 + 4 * t;
    ushort2 sv = *reinterpret_cast<const ushort2*>(base + (size_t)i * 512);
    float a0 = bf2f(sv.x), a1 = bf2f(sv.y);
    float b0 = 0.f, b1 = 0.f, c0 = 0.f, c1 = 0.f, d0 = 0.f, d1 = 0.f;
    int b = row_ptr[i], e = row_ptr[i + 1];
    int k = b;
    for (; k + 4 <= e; k += 4) {
        int s0 = srcl[k], s1 = srcl[k + 1], s2 = srcl[k + 2], s3 = srcl[k + 3];
        ushort2 v0 = *reinterpret_cast<const ushort2*>(base + (size_t)s0 * 512);
        ushort2 v1 = *reinterpret_cast<const ushort2*>(base + (size_t)s1 * 512);
        ushort2 v2 = *reinterpret_cast<const ushort2*>(base + (size_t)s2 * 512);
        ushort2 v3 = *reinterpret_cast<const ushort2*>(base + (size_t)s3 * 512);
        a0 += bf2f(v0.x); a1 += bf2f(v0.y);
        b0 += bf2f(v1.x); b1 += bf2f(v1.y);
        c0 += bf2f(v2.x); c1 += bf2f(v2.y);
        d0 += bf2f(v3.x); d1 += bf2f(v3.y);
    }
    for (; k < e; ++k) {
        int s = srcl[k];
        ushort2 v = *reinterpret_cast<const ushort2*>(base + (size_t)s * 512);
        a0 += bf2f(v.x); a1 += bf2f(v.y);
    }
    float u0 = (a0 + b0) + (c0 + d0);
    float u1 = (a1 + b1) + (c1 + d1);
    if (t == 0) u0 = 0.f;
    float s1 = wredsum(u0 * u0 + u1 * u1);
    float n = sqrtf(fmaxf(s1 + EPSF, 1e-6f));
    float fac = sinhf(fminf(n, 50.f)) / n;
    float S2 = fac * fac * s1;
    float first = sqrtf(1.f + S2);
    float dist = arcosh_f(first + EPSF);
    float C = dist / sqrtf(S2 + EPSF) * fac;
    ushort2 o;
    o.x = f2bf(C * u0);
    o.y = f2bf(C * u1);
    *reinterpret_cast<ushort2*>(Ab + (size_t)i * 256 + 2 * t) = o;
}

// ---------- W conversion (all 3 layers, one launch) ----------
__global__ void k_convw3(const float* __restrict__ W0, const float* __restrict__ W1,
                         const float* __restrict__ W2,
                         ushort_t* __restrict__ Wb0, ushort_t* __restrict__ Wb1,
                         ushort_t* __restrict__ Wb2,
                         int o1, int i1, int Kp1, int o2, int i2, int Kp2,
                         int o3, int i3, int Kp3, int t1, int t2, int t3) {
    int idx = blockIdx.x * blockDim.x + threadIdx.x;
    const float* W; ushort_t* Wb; int ncols, K, Kp, shift;
    if (idx < t1) { W = W0; Wb = Wb0; ncols = o1; K = i1; Kp = Kp1; shift = 1; }
    else if (idx < t1 + t2) { idx -= t1; W = W1; Wb = Wb1; ncols = o2; K = i2; Kp = Kp2; shift = 0; }
    else if (idx < t1 + t2 + t3) { idx -= t1 + t2; W = W2; Wb = Wb2; ncols = o3; K = i3; Kp = Kp3; shift = 0; }
    else return;
    int o = idx / Kp, kk = idx - o * Kp;
    int ks = kk - shift;
    float v = 0.f;
    if (o < ncols && ks >= 0 && ks < K) v = W[(size_t)o * K + ks];
    Wb[idx] = f2bf(v);
}

// ---------- MFMA bf16 GEMM: Yb[M x ncols] = A @ W^T + bias, bf16 output ----------
__global__ __launch_bounds__(256) void k_gemm(const ushort_t* __restrict__ Ab, int lda,
                                              const ushort_t* __restrict__ Wb, int ldw,
                                              const float* __restrict__ bias,
                                              ushort_t* __restrict__ Yb, int ldy,
                                              int Kp, int ncols) {
    __shared__ ushort_t As[128 * 32];
    __shared__ ushort_t Bs[128 * 32];
    int tid = threadIdx.x;
    int lane = tid & 63, wv = tid >> 6;
    int bm = blockIdx.x * 128, bn = blockIdx.y * 128;
    int r = lane & 15, g4 = lane >> 4;
    int wr = (wv >> 1) * 64, wc = (wv & 1) * 64;

    f32x4 acc[4][4] = {};
    for (int k0 = 0; k0 < Kp; k0 += 32) {
#pragma unroll
        for (int ci = 0; ci < 2; ++ci) {
            int L = (wv * 2 + ci) * 1024 + lane * 16;
            int row = L >> 6, kb = L & 63;
            const char* ga = (const char*)Ab + ((size_t)(bm + row) * lda + k0) * 2 + kb;
            llds16(ga, (char*)As + (wv * 2 + ci) * 1024);
            const char* gb = (const char*)Wb + ((size_t)(bn + row) * ldw + k0) * 2 + kb;
            llds16(gb, (char*)Bs + (wv * 2 + ci) * 1024);
        }
        __syncthreads();
        bf16x8 af[4], bfr[4];
#pragma unroll
        for (int m = 0; m < 4; ++m)
            af[m] = *reinterpret_cast<const bf16x8*>((const char*)As + (wr + m * 16 + r) * 64 + g4 * 16);
#pragma unroll
        for (int n2 = 0; n2 < 4; ++n2)
            bfr[n2] = *reinterpret_cast<const bf16x8*>((const char*)Bs + (wc + n2 * 16 + r) * 64 + g4 * 16);
#pragma unroll
        for (int m = 0; m < 4; ++m)
#pragma unroll
            for (int n2 = 0; n2 < 4; ++n2)
                acc[m][n2] = __builtin_amdgcn_mfma_f32_16x16x32_bf16(af[m], bfr[n2], acc[m][n2], 0, 0, 0);
        __syncthreads();
    }
#pragma unroll
    for (int n2 = 0; n2 < 4; ++n2) {
        int col = bn + wc + n2 * 16 + r;
        if (col >= ncols) continue;
        float bv = bias[col];
#pragma unroll
        for (int m = 0; m < 4; ++m) {
#pragma unroll
            for (int j = 0; j < 4; ++j) {
                int row = bm + wr + m * 16 + g4 * 4 + j;
                Yb[(size_t)row * ldy + col] = f2bf(acc[m][n2][j] + bv);
            }
        }
    }
}

// ---------- Epilogue: radial-collapsed, 1 row/wave, 4 rows/block ----------
template <int NCP>
__global__ __launch_bounds__(256) void k_ep(const ushort_t* __restrict__ Y, int ldy,
                                            ushort_t* __restrict__ out, int ldo, int N) {
    constexpr int CH = NCP / 128;
    int wv = threadIdx.x >> 6, t = threadIdx.x & 63;
    int i = blockIdx.x * 4 + wv;
    if (i >= N) return;
    const ushort_t* yr = Y + (size_t)i * ldy;
    float y[2 * CH], ym[2 * CH];
#pragma unroll
    for (int c = 0; c < CH; ++c) {
        ushort2 v = *reinterpret_cast<const ushort2*>(yr + c * 128 + 2 * t);
        y[2 * c] = bf2f(v.x);
        y[2 * c + 1] = bf2f(v.y);
    }
    if (t == 63) y[2 * CH - 1] = 0.f;  // pad column
    float s1l = 0.f, spl = 0.f;
#pragma unroll
    for (int q = 0; q < 2 * CH; ++q) {
        s1l += y[q] * y[q];
        ym[q] = fmaxf(y[q], 0.f);
        spl += ym[q] * ym[q];
    }
#pragma unroll
    for (int off = 32; off; off >>= 1) {
        s1l += __shfl_xor(s1l, off, 64);
        spl += __shfl_xor(spl, off, 64);
    }
    float s1 = s1l, sp = spl;
    bool allz = (s1 == 0.0f);
    float n1 = sqrtf(fmaxf(s1 + EPSF, 1e-6f));
    float fac1 = sinhf(fminf(n1, 50.f)) / n1;
    float S2 = allz ? 0.f : fac1 * fac1 * s1;
    float first1 = allz ? 0.f : sqrtf(1.f + S2);
    float dist = arcosh_f(first1 + EPSF);
    float rs = dist / sqrtf(S2 + EPSF);
    float coef1 = allz ? 0.f : rs * fac1;
    float S3 = coef1 * coef1 * sp;
    float n2 = sqrtf(fmaxf(S3 + EPSF, 1e-6f));
    float fac2 = sinhf(fminf(n2, 50.f)) / n2;
    float S4 = fac2 * fac2 * S3;
    float first2 = sqrtf(1.f + S4);
    float dist2 = arcosh_f(first2 + EPSF);
    float C = dist2 / sqrtf(S4 + EPSF) * fac2 * coef1;
    ushort_t* orow = out + (size_t)i * ldo;
#pragma unroll
    for (int c = 0; c < CH; ++c) {
        ushort2 o;
        o.x = f2bf(C * ym[2 * c]);
        o.y = f2bf(C * ym[2 * c + 1]);
        *reinterpret_cast<ushort2*>(orow + c * 128 + 2 * t) = o;
    }
}

// ---------- mean partials: 2048 blocks x 192 thr, ushort2 loads (deterministic) ----------
__global__ __launch_bounds__(192) void k_mean(const char* __restrict__ Rbase,
                                              float* __restrict__ partials, int N, int chunk) {
    int b = blockIdx.x;
    int t = threadIdx.x;
    int lo = b * chunk;
    int hi = lo + chunk; if (hi > N) hi = N;
    float a0 = 0.f, a1 = 0.f;
    const char* p = Rbase + (size_t)lo * 768 + 4 * t;
    for (int n = lo; n < hi; ++n, p += 768) {
        ushort2 v = *reinterpret_cast<const ushort2*>(p);
        a0 += bf2f(v.x);
        a1 += bf2f(v.y);
    }
    float* orow = partials + (size_t)b * 384;
    orow[2 * t] = a0;
    orow[2 * t + 1] = a1;
}

// ---------- stage-2 mean reduce ----------
__global__ __launch_bounds__(256) void k_mred(const float* __restrict__ partials,
                                              float* __restrict__ hm, int nparts, int N) {
    __shared__ float sb[256];
    int j = blockIdx.x, t = threadIdx.x;
    float v = 0.f;
    for (int p = t; p < nparts; p += 256) v += partials[(size_t)p * 384 + j];
    sb[t] = v; __syncthreads();
    for (int st = 128; st > 0; st >>= 1) { if (t < st) sb[t] += sb[t + st]; __syncthreads(); }
    if (t == 0) hm[j] = sb[0] / (float)N;
}

// ---------- classifier head ----------
__global__ __launch_bounds__(64) void k_head(const float* __restrict__ hm,
                                             const float* __restrict__ Wc,
                                             const float* __restrict__ bc,
                                             float* __restrict__ dout, int ic, int oc) {
    int t = threadIdx.x;
    float h[6];
    float ss = 0.f;
#pragma unroll
    for (int c = 0; c < 6; ++c) {
        int j = t + 64 * c;
        h[c] = (j < ic) ? hm[j] : 0.f;
        ss += h[c] * h[c];
    }
    float ssum = wredsum(ss);
    float dist = arcosh_f(0.0f + EPSF);
    float scl = dist / sqrtf(ssum + EPSF);
    float mxv[9];
#pragma unroll
    for (int o = 0; o < 9; ++o) {
        float p = 0.f;
        if (o < oc) {
#pragma unroll
            for (int c = 0; c < 6; ++c) {
                int j = t + 64 * c;
                if (j < ic) p += h[c] * Wc[(size_t)o * ic + j];
            }
        }
        float s = wredsum(p);
        mxv[o] = (o < oc) ? (scl * s + bc[o]) : 0.f;
    }
    if (t == 0) {
        float y[10], tt[10], lt[11], p[11], t3[11];
        float s1 = 0.f, sab = 0.f;
        for (int j = 0; j < 9; ++j) {
            y[j] = (j < oc) ? mxv[j] : 0.f;
            s1 += y[j] * y[j]; sab += fabsf(y[j]);
        }
        bool allz = (sab == 0.f);
        float n = sqrtf(fmaxf(s1 + EPSF, 1e-6f));
        float sh = sinhf(fminf(n, 50.f));
        float s2 = 0.f;
        for (int j = 0; j < oc; ++j) { tt[j] = allz ? 0.f : sh * y[j] / n; s2 += tt[j] * tt[j]; }
        float first = allz ? 0.f : sqrtf(1.f + s2);
        dout[0] = first;
        for (int j = 0; j < oc; ++j) dout[1 + j] = tt[j];
        float dist2 = arcosh_f(first + EPSF);
        float nrm2 = sqrtf(s2 + EPSF);
        lt[0] = 0.f;
        for (int j = 0; j < oc; ++j) lt[1 + j] = dist2 / nrm2 * tt[j];
        float m = lt[0];
        for (int j = 1; j <= oc; ++j) m = fmaxf(m, lt[j]);
        float es = 0.f;
        for (int j = 0; j <= oc; ++j) { p[j] = expf(lt[j] - m); es += p[j]; }
        for (int j = 0; j <= oc; ++j) p[j] /= es;
        p[0] = 0.f;
        float s3 = 0.f;
        for (int j = 1; j <= oc; ++j) s3 += p[j] * p[j];
        float n3 = sqrtf(fmaxf(s3 + EPSF, 1e-6f));
        float sh3 = sinhf(fminf(n3, 50.f));
        float s4 = 0.f;
        for (int j = 1; j <= oc; ++j) { t3[j] = sh3 * p[j] / n3; s4 += t3[j] * t3[j]; }
        dout[1 + oc] = sqrtf(1.f + s4);
        for (int j = 1; j <= oc; ++j) dout[1 + oc + j] = t3[j];
    }
}

extern "C" void kernel_launch(void* const* d_in, const int* in_sizes, int n_in,
                              void* d_out, int out_size, void* d_ws, size_t ws_size,
                              hipStream_t stream) {
    if (n_in < 10) return;
    const float* x   = (const float*)d_in[0];
    const int*   ei  = (const int*)d_in[1];
    const float* W0  = (const float*)d_in[2];
    const float* b0  = (const float*)d_in[3];
    const float* W1  = (const float*)d_in[4];
    const float* b1  = (const float*)d_in[5];
    const float* W2  = (const float*)d_in[6];
    const float* b2  = (const float*)d_in[7];
    const float* Wc  = (const float*)d_in[8];
    const float* bc  = (const float*)d_in[9];
    float* dout = (float*)d_out;

    int N = in_sizes[0] / 128;
    int E = in_sizes[1] / 2;
    int o1 = in_sizes[3];
    int i1 = in_sizes[2] / o1;
    int o2 = in_sizes[5];
    int i2 = in_sizes[4] / o2;
    int o3 = in_sizes[7];
    int i3 = in_sizes[6] / o3;
    int oc = in_sizes[9];
    int ic = in_sizes[8] / oc;

    int M_pad = ((N + 127) / 128) * 128;
    int Kp1 = ((i1 + 31) / 32) * 32;
    int Kp2 = ((i2 + 31) / 32) * 32;
    int Kp3 = ((i3 + 31) / 32) * 32;
    int Np1 = ((o1 + 127) / 128) * 128;
    int Np2 = ((o2 + 127) / 128) * 128;
    int Np3 = ((o3 + 127) / 128) * 128;

    const int* esrc = ei;
    const int* edst = ei + E;

    char* ws = (char*)d_ws;
    auto alloc = [&](size_t bytes) {
        char* p = ws;
        ws += (bytes + 511) & ~(size_t)511;
        return p;
    };
    ushort_t* Ab     = (ushort_t*)alloc((size_t)M_pad * 256 * 2);
    ushort_t* R      = (ushort_t*)alloc((size_t)M_pad * 384 * 2);
    ushort_t* Wb0    = (ushort_t*)alloc((size_t)Np1 * Kp1 * 2);
    ushort_t* Wb1    = (ushort_t*)alloc((size_t)Np2 * Kp2 * 2);
    ushort_t* Wb2    = (ushort_t*)alloc((size_t)Np3 * Kp3 * 2);
    int2*     ebuf   = (int2*)alloc((size_t)E * 8);
    int*      gcnt   = (int*)alloc((size_t)256 * 64 * 4);
    int*      bstart = (int*)alloc(128 * 4);
    int*      row_ptr= (int*)alloc((size_t)(N + 1) * 4);
    int*      srcl   = (int*)alloc((size_t)E * 4);
    float*    partials = (float*)alloc((size_t)2048 * 384 * 4);
    float*    hmbuf  = (float*)alloc(512 * 4);
    (void)ws_size;

    int NBKT = (N + 1023) >> 10;
    int EPB = 4096;
    int NBLK_E = (E + EPB - 1) / EPB;
    int rb = (N + 3) / 4;   // 4 rows per block (1 per wave)

    int t1 = Np1 * Kp1, t2 = Np2 * Kp2, t3 = Np3 * Kp3;
    k_convw3<<<dim3((t1 + t2 + t3 + 255) / 256), dim3(256), 0, stream>>>(
        W0, W1, W2, Wb0, Wb1, Wb2, o1, i1, Kp1, o2, i2, Kp2, o3, i3, Kp3, t1, t2, t3);
    // 1. log_map_zero(x) -> xt0 bf16
    k_log0<<<dim3(rb), dim3(256), 0, stream>>>(x, (char*)Ab, N);
    // 2. bucket partition + per-bucket exact CSR
    k_c1<<<dim3(NBLK_E), dim3(256), 0, stream>>>(edst, gcnt, E, NBKT, EPB);
    k_c2<<<dim3(1), dim3(64), 0, stream>>>(gcnt, bstart, NBLK_E, NBKT);
    k_c3<<<dim3(NBLK_E), dim3(256), 0, stream>>>(esrc, edst, gcnt, ebuf, E, NBKT, EPB);
    k_c4<<<dim3(NBKT), dim3(256), 0, stream>>>(ebuf, bstart, row_ptr, srcl, N, NBKT, E);
    // 3. aggregate + collapsed epilogue -> A (bf16)
    k_agg<<<dim3(rb), dim3(256), 0, stream>>>((const char*)Ab, row_ptr, srcl, Ab, N);
    // 4. layer 1
    k_gemm<<<dim3(M_pad / 128, Np1 / 128), dim3(256), 0, stream>>>(Ab, 256, Wb0, Kp1, b0, R, 128, Kp1, o1);
    k_ep<128><<<dim3(rb), dim3(256), 0, stream>>>(R, 128, Ab, 256, N);
    // 5. layer 2
    k_gemm<<<dim3(M_pad / 128, Np2 / 128), dim3(256), 0, stream>>>(Ab, 256, Wb1, Kp2, b1, R, 256, Kp2, o2);
    k_ep<256><<<dim3(rb), dim3(256), 0, stream>>>(R, 256, Ab, 256, N);
    // 6. layer 3
    k_gemm<<<dim3(M_pad / 128, Np3 / 128), dim3(256), 0, stream>>>(Ab, 256, Wb2, Kp3, b2, R, 384, Kp3, o3);
    k_ep<384><<<dim3(rb), dim3(256), 0, stream>>>(R, 384, R, 384, N);
    // 7. deterministic mean
    int NBLK = 2048;
    int chunk = (N + NBLK - 1) / NBLK;
    k_mean<<<dim3(NBLK), dim3(192), 0, stream>>>((const char*)R, partials, N, chunk);
    k_mred<<<dim3(383), dim3(256), 0, stream>>>(partials, hmbuf, NBLK, N);
    // 8. classifier head
    k_head<<<dim3(1), dim3(64), 0, stream>>>(hmbuf, Wc, bc, dout, ic, oc);
}

// Round 11
// 323.890 us; speedup vs baseline: 1.0262x; 1.0262x over previous
//
#include <hip/hip_runtime.h>
#include <math.h>

#define EPSF 1e-7f

typedef unsigned short ushort_t;
typedef __attribute__((ext_vector_type(8))) short bf16x8;
typedef __attribute__((ext_vector_type(4))) float f32x4;

__device__ __forceinline__ float arcosh_f(float x) {
    x = fmaxf(x, 1.0f + EPSF);
    return logf(x + sqrtf(x * x - 1.0f));
}

__device__ __forceinline__ unsigned short f2bf(float f) {
    union { float f; unsigned u; } c; c.f = f;
    unsigned r = c.u + 0x7FFFu + ((c.u >> 16) & 1u);
    return (unsigned short)(r >> 16);
}
__device__ __forceinline__ float bf2f(unsigned short u) {
    union { unsigned u; float f; } c; c.u = ((unsigned)u) << 16;
    return c.f;
}

__device__ __forceinline__ float wredsum(float v) {
#pragma unroll
    for (int off = 32; off; off >>= 1) v += __shfl_xor(v, off, 64);
    return v;
}

__device__ __forceinline__ void llds16(const void* g, void* l) {
    __builtin_amdgcn_global_load_lds((const __attribute__((address_space(1))) unsigned int*)g,
                                     (__attribute__((address_space(3))) unsigned int*)l,
                                     16, 0, 0);
}

// ---------- K1: xt0 = log_map_zero(x) -> bf16, upper half of Abuf rows ----------
__global__ __launch_bounds__(64) void k_log0(const float* __restrict__ x,
                                             char* __restrict__ Abase, int N) {
    int i = blockIdx.x, t = threadIdx.x;
    float2 v = *reinterpret_cast<const float2*>(x + (size_t)i * 128 + 2 * t);
    float y0 = __shfl(v.x, 0, 64);
    float a0 = (t == 0) ? 0.f : v.x;
    float s = wredsum(a0 * a0 + v.y * v.y);
    float dist = arcosh_f(y0 + EPSF);
    float scl = dist / sqrtf(s + EPSF);
    ushort2 o;
    o.x = f2bf(scl * a0);
    o.y = f2bf(scl * v.y);
    *reinterpret_cast<ushort2*>(Abase + (size_t)i * 512 + 256 + 4 * t) = o;
}

// ---------- bucket partition: 1024-node buckets ----------
__global__ __launch_bounds__(256) void k_c1(const int* __restrict__ edst,
                                            int* __restrict__ gcnt,
                                            int E, int NBKT, int EPB) {
    __shared__ int cnt[64];
    int blk = blockIdx.x, t = threadIdx.x;
    for (int i = t; i < NBKT; i += 256) cnt[i] = 0;
    __syncthreads();
    int lo = blk * EPB, hi = min(lo + EPB, E);
    for (int e = lo + t; e < hi; e += 256) atomicAdd(&cnt[edst[e] >> 10], 1);
    __syncthreads();
    for (int i = t; i < NBKT; i += 256) gcnt[blk * NBKT + i] = cnt[i];
}

__global__ __launch_bounds__(64) void k_c2(int* __restrict__ gcnt,
                                           int* __restrict__ bstart, int NBLK, int NBKT) {
    __shared__ int sh[10816];
    __shared__ int tot[64];
    __shared__ int bs[65];
    int t = threadIdx.x;
    int total = NBLK * NBKT;
    for (int i = t; i < total; i += 64) sh[i] = gcnt[i];
    __syncthreads();
    if (t < NBKT) {
        int run = 0;
        for (int blk = 0; blk < NBLK; ++blk) {
            int idx = blk * NBKT + t;
            int c = sh[idx]; sh[idx] = run; run += c;
        }
        tot[t] = run;
    }
    __syncthreads();
    if (t == 0) {
        int r = 0;
        for (int b = 0; b < NBKT; ++b) { bs[b] = r; r += tot[b]; }
        bs[NBKT] = r;
    }
    __syncthreads();
    if (t < NBKT) {
        bstart[t] = bs[t];
        if (t == 0) bstart[NBKT] = bs[NBKT];
    }
    for (int i = t; i < total; i += 64) gcnt[i] = sh[i] + bs[i % NBKT];
}

__global__ __launch_bounds__(256) void k_c3(const int* __restrict__ esrc,
                                            const int* __restrict__ edst,
                                            const int* __restrict__ gcnt,
                                            int2* __restrict__ ebuf,
                                            int E, int NBKT, int EPB) {
    __shared__ int cur[64];
    int blk = blockIdx.x, t = threadIdx.x;
    for (int i = t; i < NBKT; i += 256) cur[i] = 0;
    __syncthreads();
    int lo = blk * EPB, hi = min(lo + EPB, E);
    for (int e = lo + t; e < hi; e += 256) {
        int d = edst[e], s = esrc[e];
        int b = d >> 10;
        int r = atomicAdd(&cur[b], 1);
        ebuf[gcnt[blk * NBKT + b] + r] = make_int2(s, d);
    }
}

// ---------- c4: per-bucket exact CSR (L2-resident scatter) ----------
__global__ __launch_bounds__(256) void k_c4(const int2* __restrict__ ebuf,
                                            const int* __restrict__ bstart,
                                            int* __restrict__ row_ptr,
                                            int* __restrict__ srcl,
                                            int N, int NBKT, int E) {
    __shared__ int cnt[1024];
    __shared__ int cur[1024];
    __shared__ int sb[256];
    int b = blockIdx.x, t = threadIdx.x;
    int lo = b << 10;
    int nn = min(1024, N - lo);
    for (int i = t; i < 1024; i += 256) cnt[i] = 0;
    __syncthreads();
    int es = bstart[b], ee = bstart[b + 1];
    for (int e = es + t; e < ee; e += 256) atomicAdd(&cnt[ebuf[e].y - lo], 1);
    __syncthreads();
    int base = t * 4;
    int c0 = cnt[base], c1 = cnt[base + 1], c2 = cnt[base + 2], c3 = cnt[base + 3];
    int ts = c0 + c1 + c2 + c3;
    sb[t] = ts; __syncthreads();
    for (int st = 1; st < 256; st <<= 1) {
        int v = (t >= st) ? sb[t - st] : 0;
        __syncthreads();
        sb[t] += v;
        __syncthreads();
    }
    int run = es + sb[t] - ts;
    int rp[4];
    rp[0] = run; rp[1] = run + c0; rp[2] = rp[1] + c1; rp[3] = rp[2] + c2;
#pragma unroll
    for (int q = 0; q < 4; ++q) {
        cur[base + q] = rp[q];
        if (base + q < nn) row_ptr[lo + base + q] = rp[q];
    }
    if (b == NBKT - 1 && t == 0) row_ptr[N] = E;
    __syncthreads();
    for (int e = es + t; e < ee; e += 256) {
        int2 ed = ebuf[e];
        int r = atomicAdd(&cur[ed.y - lo], 1);
        srcl[r] = ed.x;
    }
}

// ---------- K3: agg (8-way unrolled gather) + radial-collapsed epilogue ----------
__global__ __launch_bounds__(64) void k_agg(const char* __restrict__ Abase,
                                            const int* __restrict__ row_ptr,
                                            const int* __restrict__ srcl,
                                            ushort_t* __restrict__ Ab, int N) {
    int i = blockIdx.x, t = threadIdx.x;
    const char* base = Abase + 256 + 4 * t;
    ushort2 sv = *reinterpret_cast<const ushort2*>(base + (size_t)i * 512);
    float p0[8], p1[8];
    p0[0] = bf2f(sv.x); p1[0] = bf2f(sv.y);
#pragma unroll
    for (int q = 1; q < 8; ++q) { p0[q] = 0.f; p1[q] = 0.f; }
    int b = row_ptr[i], e = row_ptr[i + 1];
    int k = b;
    for (; k + 8 <= e; k += 8) {
        int s[8];
#pragma unroll
        for (int q = 0; q < 8; ++q) s[q] = srcl[k + q];
        ushort2 v[8];
#pragma unroll
        for (int q = 0; q < 8; ++q)
            v[q] = *reinterpret_cast<const ushort2*>(base + (size_t)s[q] * 512);
#pragma unroll
        for (int q = 0; q < 8; ++q) { p0[q] += bf2f(v[q].x); p1[q] += bf2f(v[q].y); }
    }
    for (; k < e; ++k) {
        int s = srcl[k];
        ushort2 v = *reinterpret_cast<const ushort2*>(base + (size_t)s * 512);
        p0[0] += bf2f(v.x); p1[0] += bf2f(v.y);
    }
    float u0 = ((p0[0] + p0[1]) + (p0[2] + p0[3])) + ((p0[4] + p0[5]) + (p0[6] + p0[7]));
    float u1 = ((p1[0] + p1[1]) + (p1[2] + p1[3])) + ((p1[4] + p1[5]) + (p1[6] + p1[7]));
    if (t == 0) u0 = 0.f;
    float s1 = wredsum(u0 * u0 + u1 * u1);
    float n = sqrtf(fmaxf(s1 + EPSF, 1e-6f));
    float fac = sinhf(fminf(n, 50.f)) / n;
    float S2 = fac * fac * s1;
    float first = sqrtf(1.f + S2);
    float dist = arcosh_f(first + EPSF);
    float C = dist / sqrtf(S2 + EPSF) * fac;
    ushort2 o;
    o.x = f2bf(C * u0);
    o.y = f2bf(C * u1);
    *reinterpret_cast<ushort2*>(Ab + (size_t)i * 256 + 2 * t) = o;
}

// ---------- W conversion (all 3 layers, one launch) ----------
__global__ void k_convw3(const float* __restrict__ W0, const float* __restrict__ W1,
                         const float* __restrict__ W2,
                         ushort_t* __restrict__ Wb0, ushort_t* __restrict__ Wb1,
                         ushort_t* __restrict__ Wb2,
                         int o1, int i1, int Kp1, int o2, int i2, int Kp2,
                         int o3, int i3, int Kp3, int t1, int t2, int t3) {
    int idx = blockIdx.x * blockDim.x + threadIdx.x;
    const float* W; ushort_t* Wb; int ncols, K, Kp, shift;
    if (idx < t1) { W = W0; Wb = Wb0; ncols = o1; K = i1; Kp = Kp1; shift = 1; }
    else if (idx < t1 + t2) { idx -= t1; W = W1; Wb = Wb1; ncols = o2; K = i2; Kp = Kp2; shift = 0; }
    else if (idx < t1 + t2 + t3) { idx -= t1 + t2; W = W2; Wb = Wb2; ncols = o3; K = i3; Kp = Kp3; shift = 0; }
    else return;
    int o = idx / Kp, kk = idx - o * Kp;
    int ks = kk - shift;
    float v = 0.f;
    if (o < ncols && ks >= 0 && ks < K) v = W[(size_t)o * K + ks];
    Wb[idx] = f2bf(v);
}

// ---------- MFMA bf16 GEMM: Yb[M x ncols] = A @ W^T + bias, bf16 output ----------
__global__ __launch_bounds__(256) void k_gemm(const ushort_t* __restrict__ Ab, int lda,
                                              const ushort_t* __restrict__ Wb, int ldw,
                                              const float* __restrict__ bias,
                                              ushort_t* __restrict__ Yb, int ldy,
                                              int Kp, int ncols) {
    __shared__ ushort_t As[128 * 32];
    __shared__ ushort_t Bs[128 * 32];
    int tid = threadIdx.x;
    int lane = tid & 63, wv = tid >> 6;
    int bm = blockIdx.x * 128, bn = blockIdx.y * 128;
    int r = lane & 15, g4 = lane >> 4;
    int wr = (wv >> 1) * 64, wc = (wv & 1) * 64;

    f32x4 acc[4][4] = {};
    for (int k0 = 0; k0 < Kp; k0 += 32) {
#pragma unroll
        for (int ci = 0; ci < 2; ++ci) {
            int L = (wv * 2 + ci) * 1024 + lane * 16;
            int row = L >> 6, kb = L & 63;
            const char* ga = (const char*)Ab + ((size_t)(bm + row) * lda + k0) * 2 + kb;
            llds16(ga, (char*)As + (wv * 2 + ci) * 1024);
            const char* gb = (const char*)Wb + ((size_t)(bn + row) * ldw + k0) * 2 + kb;
            llds16(gb, (char*)Bs + (wv * 2 + ci) * 1024);
        }
        __syncthreads();
        bf16x8 af[4], bfr[4];
#pragma unroll
        for (int m = 0; m < 4; ++m)
            af[m] = *reinterpret_cast<const bf16x8*>((const char*)As + (wr + m * 16 + r) * 64 + g4 * 16);
#pragma unroll
        for (int n2 = 0; n2 < 4; ++n2)
            bfr[n2] = *reinterpret_cast<const bf16x8*>((const char*)Bs + (wc + n2 * 16 + r) * 64 + g4 * 16);
#pragma unroll
        for (int m = 0; m < 4; ++m)
#pragma unroll
            for (int n2 = 0; n2 < 4; ++n2)
                acc[m][n2] = __builtin_amdgcn_mfma_f32_16x16x32_bf16(af[m], bfr[n2], acc[m][n2], 0, 0, 0);
        __syncthreads();
    }
#pragma unroll
    for (int n2 = 0; n2 < 4; ++n2) {
        int col = bn + wc + n2 * 16 + r;
        if (col >= ncols) continue;
        float bv = bias[col];
#pragma unroll
        for (int m = 0; m < 4; ++m) {
#pragma unroll
            for (int j = 0; j < 4; ++j) {
                int row = bm + wr + m * 16 + g4 * 4 + j;
                Yb[(size_t)row * ldy + col] = f2bf(acc[m][n2][j] + bv);
            }
        }
    }
}

// ---------- Epilogue: radial-collapsed chain, 1 row per 64-thread block ----------
template <int NCP>
__global__ __launch_bounds__(64) void k_ep(const ushort_t* __restrict__ Y, int ldy,
                                           ushort_t* __restrict__ out, int ldo, int N) {
    constexpr int CH = NCP / 128;
    int i = blockIdx.x, t = threadIdx.x;
    const ushort_t* yr = Y + (size_t)i * ldy;
    float y[2 * CH], ym[2 * CH];
#pragma unroll
    for (int c = 0; c < CH; ++c) {
        ushort2 v = *reinterpret_cast<const ushort2*>(yr + c * 128 + 2 * t);
        y[2 * c] = bf2f(v.x);
        y[2 * c + 1] = bf2f(v.y);
    }
    if (t == 63) y[2 * CH - 1] = 0.f;  // pad column
    float s1l = 0.f, spl = 0.f;
#pragma unroll
    for (int q = 0; q < 2 * CH; ++q) {
        s1l += y[q] * y[q];
        ym[q] = fmaxf(y[q], 0.f);
        spl += ym[q] * ym[q];
    }
#pragma unroll
    for (int off = 32; off; off >>= 1) {
        s1l += __shfl_xor(s1l, off, 64);
        spl += __shfl_xor(spl, off, 64);
    }
    float s1 = s1l, sp = spl;
    bool allz = (s1 == 0.0f);
    float n1 = sqrtf(fmaxf(s1 + EPSF, 1e-6f));
    float fac1 = sinhf(fminf(n1, 50.f)) / n1;
    float S2 = allz ? 0.f : fac1 * fac1 * s1;
    float first1 = allz ? 0.f : sqrtf(1.f + S2);
    float dist = arcosh_f(first1 + EPSF);
    float rs = dist / sqrtf(S2 + EPSF);
    float coef1 = allz ? 0.f : rs * fac1;
    float S3 = coef1 * coef1 * sp;
    float n2 = sqrtf(fmaxf(S3 + EPSF, 1e-6f));
    float fac2 = sinhf(fminf(n2, 50.f)) / n2;
    float S4 = fac2 * fac2 * S3;
    float first2 = sqrtf(1.f + S4);
    float dist2 = arcosh_f(first2 + EPSF);
    float C = dist2 / sqrtf(S4 + EPSF) * fac2 * coef1;
    ushort_t* orow = out + (size_t)i * ldo;
#pragma unroll
    for (int c = 0; c < CH; ++c) {
        ushort2 o;
        o.x = f2bf(C * ym[2 * c]);
        o.y = f2bf(C * ym[2 * c + 1]);
        *reinterpret_cast<ushort2*>(orow + c * 128 + 2 * t) = o;
    }
}

// ---------- mean partials: 2048 blocks x 192 thr, ushort2 loads (deterministic) ----------
__global__ __launch_bounds__(192) void k_mean(const char* __restrict__ Rbase,
                                              float* __restrict__ partials, int N, int chunk) {
    int b = blockIdx.x;
    int t = threadIdx.x;
    int lo = b * chunk;
    int hi = lo + chunk; if (hi > N) hi = N;
    float a0 = 0.f, a1 = 0.f;
    const char* p = Rbase + (size_t)lo * 768 + 4 * t;
    for (int n = lo; n < hi; ++n, p += 768) {
        ushort2 v = *reinterpret_cast<const ushort2*>(p);
        a0 += bf2f(v.x);
        a1 += bf2f(v.y);
    }
    float* orow = partials + (size_t)b * 384;
    orow[2 * t] = a0;
    orow[2 * t + 1] = a1;
}

// ---------- stage-2 mean reduce ----------
__global__ __launch_bounds__(256) void k_mred(const float* __restrict__ partials,
                                              float* __restrict__ hm, int nparts, int N) {
    __shared__ float sb[256];
    int j = blockIdx.x, t = threadIdx.x;
    float v = 0.f;
    for (int p = t; p < nparts; p += 256) v += partials[(size_t)p * 384 + j];
    sb[t] = v; __syncthreads();
    for (int st = 128; st > 0; st >>= 1) { if (t < st) sb[t] += sb[t + st]; __syncthreads(); }
    if (t == 0) hm[j] = sb[0] / (float)N;
}

// ---------- classifier head ----------
__global__ __launch_bounds__(64) void k_head(const float* __restrict__ hm,
                                             const float* __restrict__ Wc,
                                             const float* __restrict__ bc,
                                             float* __restrict__ dout, int ic, int oc) {
    int t = threadIdx.x;
    float h[6];
    float ss = 0.f;
#pragma unroll
    for (int c = 0; c < 6; ++c) {
        int j = t + 64 * c;
        h[c] = (j < ic) ? hm[j] : 0.f;
        ss += h[c] * h[c];
    }
    float ssum = wredsum(ss);
    float dist = arcosh_f(0.0f + EPSF);
    float scl = dist / sqrtf(ssum + EPSF);
    float mxv[9];
#pragma unroll
    for (int o = 0; o < 9; ++o) {
        float p = 0.f;
        if (o < oc) {
#pragma unroll
            for (int c = 0; c < 6; ++c) {
                int j = t + 64 * c;
                if (j < ic) p += h[c] * Wc[(size_t)o * ic + j];
            }
        }
        float s = wredsum(p);
        mxv[o] = (o < oc) ? (scl * s + bc[o]) : 0.f;
    }
    if (t == 0) {
        float y[10], tt[10], lt[11], p[11], t3[11];
        float s1 = 0.f, sab = 0.f;
        for (int j = 0; j < 9; ++j) {
            y[j] = (j < oc) ? mxv[j] : 0.f;
            s1 += y[j] * y[j]; sab += fabsf(y[j]);
        }
        bool allz = (sab == 0.f);
        float n = sqrtf(fmaxf(s1 + EPSF, 1e-6f));
        float sh = sinhf(fminf(n, 50.f));
        float s2 = 0.f;
        for (int j = 0; j < oc; ++j) { tt[j] = allz ? 0.f : sh * y[j] / n; s2 += tt[j] * tt[j]; }
        float first = allz ? 0.f : sqrtf(1.f + s2);
        dout[0] = first;
        for (int j = 0; j < oc; ++j) dout[1 + j] = tt[j];
        float dist2 = arcosh_f(first + EPSF);
        float nrm2 = sqrtf(s2 + EPSF);
        lt[0] = 0.f;
        for (int j = 0; j < oc; ++j) lt[1 + j] = dist2 / nrm2 * tt[j];
        float m = lt[0];
        for (int j = 1; j <= oc; ++j) m = fmaxf(m, lt[j]);
        float es = 0.f;
        for (int j = 0; j <= oc; ++j) { p[j] = expf(lt[j] - m); es += p[j]; }
        for (int j = 0; j <= oc; ++j) p[j] /= es;
        p[0] = 0.f;
        float s3 = 0.f;
        for (int j = 1; j <= oc; ++j) s3 += p[j] * p[j];
        float n3 = sqrtf(fmaxf(s3 + EPSF, 1e-6f));
        float sh3 = sinhf(fminf(n3, 50.f));
        float s4 = 0.f;
        for (int j = 1; j <= oc; ++j) { t3[j] = sh3 * p[j] / n3; s4 += t3[j] * t3[j]; }
        dout[1 + oc] = sqrtf(1.f + s4);
        for (int j = 1; j <= oc; ++j) dout[1 + oc + j] = t3[j];
    }
}

extern "C" void kernel_launch(void* const* d_in, const int* in_sizes, int n_in,
                              void* d_out, int out_size, void* d_ws, size_t ws_size,
                              hipStream_t stream) {
    if (n_in < 10) return;
    const float* x   = (const float*)d_in[0];
    const int*   ei  = (const int*)d_in[1];
    const float* W0  = (const float*)d_in[2];
    const float* b0  = (const float*)d_in[3];
    const float* W1  = (const float*)d_in[4];
    const float* b1  = (const float*)d_in[5];
    const float* W2  = (const float*)d_in[6];
    const float* b2  = (const float*)d_in[7];
    const float* Wc  = (const float*)d_in[8];
    const float* bc  = (const float*)d_in[9];
    float* dout = (float*)d_out;

    int N = in_sizes[0] / 128;
    int E = in_sizes[1] / 2;
    int o1 = in_sizes[3];
    int i1 = in_sizes[2] / o1;
    int o2 = in_sizes[5];
    int i2 = in_sizes[4] / o2;
    int o3 = in_sizes[7];
    int i3 = in_sizes[6] / o3;
    int oc = in_sizes[9];
    int ic = in_sizes[8] / oc;

    int M_pad = ((N + 127) / 128) * 128;
    int Kp1 = ((i1 + 31) / 32) * 32;
    int Kp2 = ((i2 + 31) / 32) * 32;
    int Kp3 = ((i3 + 31) / 32) * 32;
    int Np1 = ((o1 + 127) / 128) * 128;
    int Np2 = ((o2 + 127) / 128) * 128;
    int Np3 = ((o3 + 127) / 128) * 128;

    const int* esrc = ei;
    const int* edst = ei + E;

    char* ws = (char*)d_ws;
    auto alloc = [&](size_t bytes) {
        char* p = ws;
        ws += (bytes + 511) & ~(size_t)511;
        return p;
    };
    ushort_t* Ab     = (ushort_t*)alloc((size_t)M_pad * 256 * 2);
    ushort_t* R      = (ushort_t*)alloc((size_t)M_pad * 384 * 2);
    ushort_t* Wb0    = (ushort_t*)alloc((size_t)Np1 * Kp1 * 2);
    ushort_t* Wb1    = (ushort_t*)alloc((size_t)Np2 * Kp2 * 2);
    ushort_t* Wb2    = (ushort_t*)alloc((size_t)Np3 * Kp3 * 2);
    int2*     ebuf   = (int2*)alloc((size_t)E * 8);
    int*      gcnt   = (int*)alloc((size_t)256 * 64 * 4);
    int*      bstart = (int*)alloc(128 * 4);
    int*      row_ptr= (int*)alloc((size_t)(N + 1) * 4);
    int*      srcl   = (int*)alloc((size_t)E * 4);
    float*    partials = (float*)alloc((size_t)2048 * 384 * 4);
    float*    hmbuf  = (float*)alloc(512 * 4);
    (void)ws_size;

    int NBKT = (N + 1023) >> 10;
    int EPB = 4096;
    int NBLK_E = (E + EPB - 1) / EPB;

    int t1 = Np1 * Kp1, t2 = Np2 * Kp2, t3 = Np3 * Kp3;
    k_convw3<<<dim3((t1 + t2 + t3 + 255) / 256), dim3(256), 0, stream>>>(
        W0, W1, W2, Wb0, Wb1, Wb2, o1, i1, Kp1, o2, i2, Kp2, o3, i3, Kp3, t1, t2, t3);
    // 1. log_map_zero(x) -> xt0 bf16
    k_log0<<<dim3(N), dim3(64), 0, stream>>>(x, (char*)Ab, N);
    // 2. bucket partition + per-bucket exact CSR
    k_c1<<<dim3(NBLK_E), dim3(256), 0, stream>>>(edst, gcnt, E, NBKT, EPB);
    k_c2<<<dim3(1), dim3(64), 0, stream>>>(gcnt, bstart, NBLK_E, NBKT);
    k_c3<<<dim3(NBLK_E), dim3(256), 0, stream>>>(esrc, edst, gcnt, ebuf, E, NBKT, EPB);
    k_c4<<<dim3(NBKT), dim3(256), 0, stream>>>(ebuf, bstart, row_ptr, srcl, N, NBKT, E);
    // 3. aggregate (8-way MLP gather) + collapsed epilogue -> A (bf16)
    k_agg<<<dim3(N), dim3(64), 0, stream>>>((const char*)Ab, row_ptr, srcl, Ab, N);
    // 4. layer 1
    k_gemm<<<dim3(M_pad / 128, Np1 / 128), dim3(256), 0, stream>>>(Ab, 256, Wb0, Kp1, b0, R, 128, Kp1, o1);
    k_ep<128><<<dim3(N), dim3(64), 0, stream>>>(R, 128, Ab, 256, N);
    // 5. layer 2
    k_gemm<<<dim3(M_pad / 128, Np2 / 128), dim3(256), 0, stream>>>(Ab, 256, Wb1, Kp2, b1, R, 256, Kp2, o2);
    k_ep<256><<<dim3(N), dim3(64), 0, stream>>>(R, 256, Ab, 256, N);
    // 6. layer 3
    k_gemm<<<dim3(M_pad / 128, Np3 / 128), dim3(256), 0, stream>>>(Ab, 256, Wb2, Kp3, b2, R, 384, Kp3, o3);
    k_ep<384><<<dim3(N), dim3(64), 0, stream>>>(R, 384, R, 384, N);
    // 7. deterministic mean
    int NBLK = 2048;
    int chunk = (N + NBLK - 1) / NBLK;
    k_mean<<<dim3(NBLK), dim3(192), 0, stream>>>((const char*)R, partials, N, chunk);
    k_mred<<<dim3(383), dim3(256), 0, stream>>>(partials, hmbuf, NBLK, N);
    // 8. classifier head
    k_head<<<dim3(1), dim3(64), 0, stream>>>(hmbuf, Wc, bc, dout, ic, oc);
}

// Round 12
// 320.345 us; speedup vs baseline: 1.0375x; 1.0111x over previous
//
#include <hip/hip_runtime.h>
#include <math.h>

#define EPSF 1e-7f

typedef unsigned short ushort_t;
typedef __attribute__((ext_vector_type(8))) short bf16x8;
typedef __attribute__((ext_vector_type(4))) float f32x4;

__device__ __forceinline__ float arcosh_f(float x) {
    x = fmaxf(x, 1.0f + EPSF);
    return logf(x + sqrtf(x * x - 1.0f));
}

__device__ __forceinline__ unsigned short f2bf(float f) {
    union { float f; unsigned u; } c; c.f = f;
    unsigned r = c.u + 0x7FFFu + ((c.u >> 16) & 1u);
    return (unsigned short)(r >> 16);
}
__device__ __forceinline__ float bf2f(unsigned short u) {
    union { unsigned u; float f; } c; c.u = ((unsigned)u) << 16;
    return c.f;
}

__device__ __forceinline__ float wredsum(float v) {
#pragma unroll
    for (int off = 32; off; off >>= 1) v += __shfl_xor(v, off, 64);
    return v;
}

__device__ __forceinline__ void llds16(const void* g, void* l) {
    __builtin_amdgcn_global_load_lds((const __attribute__((address_space(1))) unsigned int*)g,
                                     (__attribute__((address_space(3))) unsigned int*)l,
                                     16, 0, 0);
}

// ---------- K1: xt0 = log_map_zero(x) -> bf16, upper half of Abuf rows ----------
__global__ __launch_bounds__(64) void k_log0(const float* __restrict__ x,
                                             char* __restrict__ Abase, int N) {
    int i = blockIdx.x, t = threadIdx.x;
    float2 v = *reinterpret_cast<const float2*>(x + (size_t)i * 128 + 2 * t);
    float y0 = __shfl(v.x, 0, 64);
    float a0 = (t == 0) ? 0.f : v.x;
    float s = wredsum(a0 * a0 + v.y * v.y);
    float dist = arcosh_f(y0 + EPSF);
    float scl = dist / sqrtf(s + EPSF);
    ushort2 o;
    o.x = f2bf(scl * a0);
    o.y = f2bf(scl * v.y);
    *reinterpret_cast<ushort2*>(Abase + (size_t)i * 512 + 256 + 4 * t) = o;
}

// ---------- bucket partition: 1024-node buckets ----------
__global__ __launch_bounds__(256) void k_c1(const int* __restrict__ edst,
                                            int* __restrict__ gcnt,
                                            int E, int NBKT, int EPB) {
    __shared__ int cnt[64];
    int blk = blockIdx.x, t = threadIdx.x;
    for (int i = t; i < NBKT; i += 256) cnt[i] = 0;
    __syncthreads();
    int lo = blk * EPB, hi = min(lo + EPB, E);
    for (int e = lo + t; e < hi; e += 256) atomicAdd(&cnt[edst[e] >> 10], 1);
    __syncthreads();
    for (int i = t; i < NBKT; i += 256) gcnt[blk * NBKT + i] = cnt[i];
}

__global__ __launch_bounds__(64) void k_c2(int* __restrict__ gcnt,
                                           int* __restrict__ bstart, int NBLK, int NBKT) {
    __shared__ int sh[10816];
    __shared__ int tot[64];
    __shared__ int bs[65];
    int t = threadIdx.x;
    int total = NBLK * NBKT;
    for (int i = t; i < total; i += 64) sh[i] = gcnt[i];
    __syncthreads();
    if (t < NBKT) {
        int run = 0;
        for (int blk = 0; blk < NBLK; ++blk) {
            int idx = blk * NBKT + t;
            int c = sh[idx]; sh[idx] = run; run += c;
        }
        tot[t] = run;
    }
    __syncthreads();
    if (t == 0) {
        int r = 0;
        for (int b = 0; b < NBKT; ++b) { bs[b] = r; r += tot[b]; }
        bs[NBKT] = r;
    }
    __syncthreads();
    if (t < NBKT) {
        bstart[t] = bs[t];
        if (t == 0) bstart[NBKT] = bs[NBKT];
    }
    for (int i = t; i < total; i += 64) gcnt[i] = sh[i] + bs[i % NBKT];
}

__global__ __launch_bounds__(256) void k_c3(const int* __restrict__ esrc,
                                            const int* __restrict__ edst,
                                            const int* __restrict__ gcnt,
                                            int2* __restrict__ ebuf,
                                            int E, int NBKT, int EPB) {
    __shared__ int cur[64];
    int blk = blockIdx.x, t = threadIdx.x;
    for (int i = t; i < NBKT; i += 256) cur[i] = 0;
    __syncthreads();
    int lo = blk * EPB, hi = min(lo + EPB, E);
    for (int e = lo + t; e < hi; e += 256) {
        int d = edst[e], s = esrc[e];
        int b = d >> 10;
        int r = atomicAdd(&cur[b], 1);
        ebuf[gcnt[blk * NBKT + b] + r] = make_int2(s, d);
    }
}

// ---------- c4: per-bucket exact CSR (L2-resident scatter) ----------
__global__ __launch_bounds__(256) void k_c4(const int2* __restrict__ ebuf,
                                            const int* __restrict__ bstart,
                                            int* __restrict__ row_ptr,
                                            int* __restrict__ srcl,
                                            int N, int NBKT, int E) {
    __shared__ int cnt[1024];
    __shared__ int cur[1024];
    __shared__ int sb[256];
    int b = blockIdx.x, t = threadIdx.x;
    int lo = b << 10;
    int nn = min(1024, N - lo);
    for (int i = t; i < 1024; i += 256) cnt[i] = 0;
    __syncthreads();
    int es = bstart[b], ee = bstart[b + 1];
    for (int e = es + t; e < ee; e += 256) atomicAdd(&cnt[ebuf[e].y - lo], 1);
    __syncthreads();
    int base = t * 4;
    int c0 = cnt[base], c1 = cnt[base + 1], c2 = cnt[base + 2], c3 = cnt[base + 3];
    int ts = c0 + c1 + c2 + c3;
    sb[t] = ts; __syncthreads();
    for (int st = 1; st < 256; st <<= 1) {
        int v = (t >= st) ? sb[t - st] : 0;
        __syncthreads();
        sb[t] += v;
        __syncthreads();
    }
    int run = es + sb[t] - ts;
    int rp[4];
    rp[0] = run; rp[1] = run + c0; rp[2] = rp[1] + c1; rp[3] = rp[2] + c2;
#pragma unroll
    for (int q = 0; q < 4; ++q) {
        cur[base + q] = rp[q];
        if (base + q < nn) row_ptr[lo + base + q] = rp[q];
    }
    if (b == NBKT - 1 && t == 0) row_ptr[N] = E;
    __syncthreads();
    for (int e = es + t; e < ee; e += 256) {
        int2 ed = ebuf[e];
        int r = atomicAdd(&cur[ed.y - lo], 1);
        srcl[r] = ed.x;
    }
}

// ---------- K3: agg (8-way unrolled gather) + radial-collapsed epilogue ----------
__global__ __launch_bounds__(64) void k_agg(const char* __restrict__ Abase,
                                            const int* __restrict__ row_ptr,
                                            const int* __restrict__ srcl,
                                            ushort_t* __restrict__ Ab, int N) {
    int i = blockIdx.x, t = threadIdx.x;
    const char* base = Abase + 256 + 4 * t;
    ushort2 sv = *reinterpret_cast<const ushort2*>(base + (size_t)i * 512);
    float p0[8], p1[8];
    p0[0] = bf2f(sv.x); p1[0] = bf2f(sv.y);
#pragma unroll
    for (int q = 1; q < 8; ++q) { p0[q] = 0.f; p1[q] = 0.f; }
    int b = row_ptr[i], e = row_ptr[i + 1];
    int k = b;
    for (; k + 8 <= e; k += 8) {
        int s[8];
#pragma unroll
        for (int q = 0; q < 8; ++q) s[q] = srcl[k + q];
        ushort2 v[8];
#pragma unroll
        for (int q = 0; q < 8; ++q)
            v[q] = *reinterpret_cast<const ushort2*>(base + (size_t)s[q] * 512);
#pragma unroll
        for (int q = 0; q < 8; ++q) { p0[q] += bf2f(v[q].x); p1[q] += bf2f(v[q].y); }
    }
    for (; k < e; ++k) {
        int s = srcl[k];
        ushort2 v = *reinterpret_cast<const ushort2*>(base + (size_t)s * 512);
        p0[0] += bf2f(v.x); p1[0] += bf2f(v.y);
    }
    float u0 = ((p0[0] + p0[1]) + (p0[2] + p0[3])) + ((p0[4] + p0[5]) + (p0[6] + p0[7]));
    float u1 = ((p1[0] + p1[1]) + (p1[2] + p1[3])) + ((p1[4] + p1[5]) + (p1[6] + p1[7]));
    if (t == 0) u0 = 0.f;
    float s1 = wredsum(u0 * u0 + u1 * u1);
    float n = sqrtf(fmaxf(s1 + EPSF, 1e-6f));
    float fac = sinhf(fminf(n, 50.f)) / n;
    float S2 = fac * fac * s1;
    float first = sqrtf(1.f + S2);
    float dist = arcosh_f(first + EPSF);
    float C = dist / sqrtf(S2 + EPSF) * fac;
    ushort2 o;
    o.x = f2bf(C * u0);
    o.y = f2bf(C * u1);
    *reinterpret_cast<ushort2*>(Ab + (size_t)i * 256 + 2 * t) = o;
}

// ---------- W conversion (all 3 layers, one launch) ----------
__global__ void k_convw3(const float* __restrict__ W0, const float* __restrict__ W1,
                         const float* __restrict__ W2,
                         ushort_t* __restrict__ Wb0, ushort_t* __restrict__ Wb1,
                         ushort_t* __restrict__ Wb2,
                         int o1, int i1, int Kp1, int o2, int i2, int Kp2,
                         int o3, int i3, int Kp3, int t1, int t2, int t3) {
    int idx = blockIdx.x * blockDim.x + threadIdx.x;
    const float* W; ushort_t* Wb; int ncols, K, Kp, shift;
    if (idx < t1) { W = W0; Wb = Wb0; ncols = o1; K = i1; Kp = Kp1; shift = 1; }
    else if (idx < t1 + t2) { idx -= t1; W = W1; Wb = Wb1; ncols = o2; K = i2; Kp = Kp2; shift = 0; }
    else if (idx < t1 + t2 + t3) { idx -= t1 + t2; W = W2; Wb = Wb2; ncols = o3; K = i3; Kp = Kp3; shift = 0; }
    else return;
    int o = idx / Kp, kk = idx - o * Kp;
    int ks = kk - shift;
    float v = 0.f;
    if (o < ncols && ks >= 0 && ks < K) v = W[(size_t)o * K + ks];
    Wb[idx] = f2bf(v);
}

// ---------- MFMA bf16 GEMM: Yb[M x ncols] = A @ W^T + bias, bf16 output ----------
__global__ __launch_bounds__(256) void k_gemm(const ushort_t* __restrict__ Ab, int lda,
                                              const ushort_t* __restrict__ Wb, int ldw,
                                              const float* __restrict__ bias,
                                              ushort_t* __restrict__ Yb, int ldy,
                                              int Kp, int ncols) {
    __shared__ ushort_t As[128 * 32];
    __shared__ ushort_t Bs[128 * 32];
    int tid = threadIdx.x;
    int lane = tid & 63, wv = tid >> 6;
    int bm = blockIdx.x * 128, bn = blockIdx.y * 128;
    int r = lane & 15, g4 = lane >> 4;
    int wr = (wv >> 1) * 64, wc = (wv & 1) * 64;

    f32x4 acc[4][4] = {};
    for (int k0 = 0; k0 < Kp; k0 += 32) {
#pragma unroll
        for (int ci = 0; ci < 2; ++ci) {
            int L = (wv * 2 + ci) * 1024 + lane * 16;
            int row = L >> 6, kb = L & 63;
            const char* ga = (const char*)Ab + ((size_t)(bm + row) * lda + k0) * 2 + kb;
            llds16(ga, (char*)As + (wv * 2 + ci) * 1024);
            const char* gb = (const char*)Wb + ((size_t)(bn + row) * ldw + k0) * 2 + kb;
            llds16(gb, (char*)Bs + (wv * 2 + ci) * 1024);
        }
        __syncthreads();
        bf16x8 af[4], bfr[4];
#pragma unroll
        for (int m = 0; m < 4; ++m)
            af[m] = *reinterpret_cast<const bf16x8*>((const char*)As + (wr + m * 16 + r) * 64 + g4 * 16);
#pragma unroll
        for (int n2 = 0; n2 < 4; ++n2)
            bfr[n2] = *reinterpret_cast<const bf16x8*>((const char*)Bs + (wc + n2 * 16 + r) * 64 + g4 * 16);
#pragma unroll
        for (int m = 0; m < 4; ++m)
#pragma unroll
            for (int n2 = 0; n2 < 4; ++n2)
                acc[m][n2] = __builtin_amdgcn_mfma_f32_16x16x32_bf16(af[m], bfr[n2], acc[m][n2], 0, 0, 0);
        __syncthreads();
    }
#pragma unroll
    for (int n2 = 0; n2 < 4; ++n2) {
        int col = bn + wc + n2 * 16 + r;
        if (col >= ncols) continue;
        float bv = bias[col];
#pragma unroll
        for (int m = 0; m < 4; ++m) {
#pragma unroll
            for (int j = 0; j < 4; ++j) {
                int row = bm + wr + m * 16 + g4 * 4 + j;
                Yb[(size_t)row * ldy + col] = f2bf(acc[m][n2][j] + bv);
            }
        }
    }
}

// ---------- Epilogue: radial-collapsed chain, 1 row per 64-thread block ----------
template <int NCP>
__global__ __launch_bounds__(64) void k_ep(const ushort_t* __restrict__ Y, int ldy,
                                           ushort_t* __restrict__ out, int ldo, int N) {
    constexpr int CH = NCP / 128;
    int i = blockIdx.x, t = threadIdx.x;
    const ushort_t* yr = Y + (size_t)i * ldy;
    float y[2 * CH], ym[2 * CH];
#pragma unroll
    for (int c = 0; c < CH; ++c) {
        ushort2 v = *reinterpret_cast<const ushort2*>(yr + c * 128 + 2 * t);
        y[2 * c] = bf2f(v.x);
        y[2 * c + 1] = bf2f(v.y);
    }
    if (t == 63) y[2 * CH - 1] = 0.f;  // pad column
    float s1l = 0.f, spl = 0.f;
#pragma unroll
    for (int q = 0; q < 2 * CH; ++q) {
        s1l += y[q] * y[q];
        ym[q] = fmaxf(y[q], 0.f);
        spl += ym[q] * ym[q];
    }
#pragma unroll
    for (int off = 32; off; off >>= 1) {
        s1l += __shfl_xor(s1l, off, 64);
        spl += __shfl_xor(spl, off, 64);
    }
    float s1 = s1l, sp = spl;
    bool allz = (s1 == 0.0f);
    float n1 = sqrtf(fmaxf(s1 + EPSF, 1e-6f));
    float fac1 = sinhf(fminf(n1, 50.f)) / n1;
    float S2 = allz ? 0.f : fac1 * fac1 * s1;
    float first1 = allz ? 0.f : sqrtf(1.f + S2);
    float dist = arcosh_f(first1 + EPSF);
    float rs = dist / sqrtf(S2 + EPSF);
    float coef1 = allz ? 0.f : rs * fac1;
    float S3 = coef1 * coef1 * sp;
    float n2 = sqrtf(fmaxf(S3 + EPSF, 1e-6f));
    float fac2 = sinhf(fminf(n2, 50.f)) / n2;
    float S4 = fac2 * fac2 * S3;
    float first2 = sqrtf(1.f + S4);
    float dist2 = arcosh_f(first2 + EPSF);
    float C = dist2 / sqrtf(S4 + EPSF) * fac2 * coef1;
    ushort_t* orow = out + (size_t)i * ldo;
#pragma unroll
    for (int c = 0; c < CH; ++c) {
        ushort2 o;
        o.x = f2bf(C * ym[2 * c]);
        o.y = f2bf(C * ym[2 * c + 1]);
        *reinterpret_cast<ushort2*>(orow + c * 128 + 2 * t) = o;
    }
}

// ---------- k_coef: layer-3 epilogue coefficient only (no ht write) ----------
__global__ __launch_bounds__(64) void k_coef(const ushort_t* __restrict__ Y, int ldy,
                                             float* __restrict__ coef, int N) {
    constexpr int CH = 3;
    int i = blockIdx.x, t = threadIdx.x;
    const ushort_t* yr = Y + (size_t)i * ldy;
    float y[2 * CH];
#pragma unroll
    for (int c = 0; c < CH; ++c) {
        ushort2 v = *reinterpret_cast<const ushort2*>(yr + c * 128 + 2 * t);
        y[2 * c] = bf2f(v.x);
        y[2 * c + 1] = bf2f(v.y);
    }
    if (t == 63) y[2 * CH - 1] = 0.f;  // pad column 383
    float s1l = 0.f, spl = 0.f;
#pragma unroll
    for (int q = 0; q < 2 * CH; ++q) {
        s1l += y[q] * y[q];
        float m = fmaxf(y[q], 0.f);
        spl += m * m;
    }
#pragma unroll
    for (int off = 32; off; off >>= 1) {
        s1l += __shfl_xor(s1l, off, 64);
        spl += __shfl_xor(spl, off, 64);
    }
    float s1 = s1l, sp = spl;
    bool allz = (s1 == 0.0f);
    float n1 = sqrtf(fmaxf(s1 + EPSF, 1e-6f));
    float fac1 = sinhf(fminf(n1, 50.f)) / n1;
    float S2 = allz ? 0.f : fac1 * fac1 * s1;
    float first1 = allz ? 0.f : sqrtf(1.f + S2);
    float dist = arcosh_f(first1 + EPSF);
    float rs = dist / sqrtf(S2 + EPSF);
    float coef1 = allz ? 0.f : rs * fac1;
    float S3 = coef1 * coef1 * sp;
    float n2 = sqrtf(fmaxf(S3 + EPSF, 1e-6f));
    float fac2 = sinhf(fminf(n2, 50.f)) / n2;
    float S4 = fac2 * fac2 * S3;
    float first2 = sqrtf(1.f + S4);
    float dist2 = arcosh_f(first2 + EPSF);
    float C = dist2 / sqrtf(S4 + EPSF) * fac2 * coef1;
    if (t == 0) coef[i] = C;
}

// ---------- mean partials: reads Y + coef, accumulates C*relu(y). deterministic ----------
__global__ __launch_bounds__(192) void k_mean(const ushort_t* __restrict__ Y,
                                              const float* __restrict__ coef,
                                              float* __restrict__ partials, int N, int chunk) {
    int b = blockIdx.x;
    int t = threadIdx.x;
    int lo = b * chunk;
    int hi = lo + chunk; if (hi > N) hi = N;
    bool lastpair = (t == 191);     // col 383 is pad (garbage) -> exclude
    float a0 = 0.f, a1 = 0.f;
    const ushort_t* p = Y + (size_t)lo * 384 + 2 * t;
    for (int n = lo; n < hi; ++n, p += 384) {
        float c = coef[n];
        ushort2 v = *reinterpret_cast<const ushort2*>(p);
        a0 += c * fmaxf(bf2f(v.x), 0.f);
        if (!lastpair) a1 += c * fmaxf(bf2f(v.y), 0.f);
    }
    float* orow = partials + (size_t)b * 384;
    orow[2 * t] = a0;
    orow[2 * t + 1] = a1;
}

// ---------- stage-2 mean reduce ----------
__global__ __launch_bounds__(256) void k_mred(const float* __restrict__ partials,
                                              float* __restrict__ hm, int nparts, int N) {
    __shared__ float sb[256];
    int j = blockIdx.x, t = threadIdx.x;
    float v = 0.f;
    for (int p = t; p < nparts; p += 256) v += partials[(size_t)p * 384 + j];
    sb[t] = v; __syncthreads();
    for (int st = 128; st > 0; st >>= 1) { if (t < st) sb[t] += sb[t + st]; __syncthreads(); }
    if (t == 0) hm[j] = sb[0] / (float)N;
}

// ---------- classifier head ----------
__global__ __launch_bounds__(64) void k_head(const float* __restrict__ hm,
                                             const float* __restrict__ Wc,
                                             const float* __restrict__ bc,
                                             float* __restrict__ dout, int ic, int oc) {
    int t = threadIdx.x;
    float h[6];
    float ss = 0.f;
#pragma unroll
    for (int c = 0; c < 6; ++c) {
        int j = t + 64 * c;
        h[c] = (j < ic) ? hm[j] : 0.f;
        ss += h[c] * h[c];
    }
    float ssum = wredsum(ss);
    float dist = arcosh_f(0.0f + EPSF);
    float scl = dist / sqrtf(ssum + EPSF);
    float mxv[9];
#pragma unroll
    for (int o = 0; o < 9; ++o) {
        float p = 0.f;
        if (o < oc) {
#pragma unroll
            for (int c = 0; c < 6; ++c) {
                int j = t + 64 * c;
                if (j < ic) p += h[c] * Wc[(size_t)o * ic + j];
            }
        }
        float s = wredsum(p);
        mxv[o] = (o < oc) ? (scl * s + bc[o]) : 0.f;
    }
    if (t == 0) {
        float y[10], tt[10], lt[11], p[11], t3[11];
        float s1 = 0.f, sab = 0.f;
        for (int j = 0; j < 9; ++j) {
            y[j] = (j < oc) ? mxv[j] : 0.f;
            s1 += y[j] * y[j]; sab += fabsf(y[j]);
        }
        bool allz = (sab == 0.f);
        float n = sqrtf(fmaxf(s1 + EPSF, 1e-6f));
        float sh = sinhf(fminf(n, 50.f));
        float s2 = 0.f;
        for (int j = 0; j < oc; ++j) { tt[j] = allz ? 0.f : sh * y[j] / n; s2 += tt[j] * tt[j]; }
        float first = allz ? 0.f : sqrtf(1.f + s2);
        dout[0] = first;
        for (int j = 0; j < oc; ++j) dout[1 + j] = tt[j];
        float dist2 = arcosh_f(first + EPSF);
        float nrm2 = sqrtf(s2 + EPSF);
        lt[0] = 0.f;
        for (int j = 0; j < oc; ++j) lt[1 + j] = dist2 / nrm2 * tt[j];
        float m = lt[0];
        for (int j = 1; j <= oc; ++j) m = fmaxf(m, lt[j]);
        float es = 0.f;
        for (int j = 0; j <= oc; ++j) { p[j] = expf(lt[j] - m); es += p[j]; }
        for (int j = 0; j <= oc; ++j) p[j] /= es;
        p[0] = 0.f;
        float s3 = 0.f;
        for (int j = 1; j <= oc; ++j) s3 += p[j] * p[j];
        float n3 = sqrtf(fmaxf(s3 + EPSF, 1e-6f));
        float sh3 = sinhf(fminf(n3, 50.f));
        float s4 = 0.f;
        for (int j = 1; j <= oc; ++j) { t3[j] = sh3 * p[j] / n3; s4 += t3[j] * t3[j]; }
        dout[1 + oc] = sqrtf(1.f + s4);
        for (int j = 1; j <= oc; ++j) dout[1 + oc + j] = t3[j];
    }
}

extern "C" void kernel_launch(void* const* d_in, const int* in_sizes, int n_in,
                              void* d_out, int out_size, void* d_ws, size_t ws_size,
                              hipStream_t stream) {
    if (n_in < 10) return;
    const float* x   = (const float*)d_in[0];
    const int*   ei  = (const int*)d_in[1];
    const float* W0  = (const float*)d_in[2];
    const float* b0  = (const float*)d_in[3];
    const float* W1  = (const float*)d_in[4];
    const float* b1  = (const float*)d_in[5];
    const float* W2  = (const float*)d_in[6];
    const float* b2  = (const float*)d_in[7];
    const float* Wc  = (const float*)d_in[8];
    const float* bc  = (const float*)d_in[9];
    float* dout = (float*)d_out;

    int N = in_sizes[0] / 128;
    int E = in_sizes[1] / 2;
    int o1 = in_sizes[3];
    int i1 = in_sizes[2] / o1;
    int o2 = in_sizes[5];
    int i2 = in_sizes[4] / o2;
    int o3 = in_sizes[7];
    int i3 = in_sizes[6] / o3;
    int oc = in_sizes[9];
    int ic = in_sizes[8] / oc;

    int M_pad = ((N + 127) / 128) * 128;
    int Kp1 = ((i1 + 31) / 32) * 32;
    int Kp2 = ((i2 + 31) / 32) * 32;
    int Kp3 = ((i3 + 31) / 32) * 32;
    int Np1 = ((o1 + 127) / 128) * 128;
    int Np2 = ((o2 + 127) / 128) * 128;
    int Np3 = ((o3 + 127) / 128) * 128;

    const int* esrc = ei;
    const int* edst = ei + E;

    char* ws = (char*)d_ws;
    auto alloc = [&](size_t bytes) {
        char* p = ws;
        ws += (bytes + 511) & ~(size_t)511;
        return p;
    };
    ushort_t* Ab     = (ushort_t*)alloc((size_t)M_pad * 256 * 2);
    ushort_t* R      = (ushort_t*)alloc((size_t)M_pad * 384 * 2);
    ushort_t* Wb0    = (ushort_t*)alloc((size_t)Np1 * Kp1 * 2);
    ushort_t* Wb1    = (ushort_t*)alloc((size_t)Np2 * Kp2 * 2);
    ushort_t* Wb2    = (ushort_t*)alloc((size_t)Np3 * Kp3 * 2);
    int2*     ebuf   = (int2*)alloc((size_t)E * 8);
    int*      gcnt   = (int*)alloc((size_t)256 * 64 * 4);
    int*      bstart = (int*)alloc(128 * 4);
    int*      row_ptr= (int*)alloc((size_t)(N + 1) * 4);
    int*      srcl   = (int*)alloc((size_t)E * 4);
    float*    coefb  = (float*)alloc((size_t)N * 4);
    float*    partials = (float*)alloc((size_t)2048 * 384 * 4);
    float*    hmbuf  = (float*)alloc(512 * 4);
    (void)ws_size;

    int NBKT = (N + 1023) >> 10;
    int EPB = 4096;
    int NBLK_E = (E + EPB - 1) / EPB;

    int t1 = Np1 * Kp1, t2 = Np2 * Kp2, t3 = Np3 * Kp3;
    k_convw3<<<dim3((t1 + t2 + t3 + 255) / 256), dim3(256), 0, stream>>>(
        W0, W1, W2, Wb0, Wb1, Wb2, o1, i1, Kp1, o2, i2, Kp2, o3, i3, Kp3, t1, t2, t3);
    // 1. log_map_zero(x) -> xt0 bf16
    k_log0<<<dim3(N), dim3(64), 0, stream>>>(x, (char*)Ab, N);
    // 2. bucket partition + per-bucket exact CSR
    k_c1<<<dim3(NBLK_E), dim3(256), 0, stream>>>(edst, gcnt, E, NBKT, EPB);
    k_c2<<<dim3(1), dim3(64), 0, stream>>>(gcnt, bstart, NBLK_E, NBKT);
    k_c3<<<dim3(NBLK_E), dim3(256), 0, stream>>>(esrc, edst, gcnt, ebuf, E, NBKT, EPB);
    k_c4<<<dim3(NBKT), dim3(256), 0, stream>>>(ebuf, bstart, row_ptr, srcl, N, NBKT, E);
    // 3. aggregate (8-way MLP gather) + collapsed epilogue -> A (bf16)
    k_agg<<<dim3(N), dim3(64), 0, stream>>>((const char*)Ab, row_ptr, srcl, Ab, N);
    // 4. layer 1
    k_gemm<<<dim3(M_pad / 128, Np1 / 128), dim3(256), 0, stream>>>(Ab, 256, Wb0, Kp1, b0, R, 128, Kp1, o1);
    k_ep<128><<<dim3(N), dim3(64), 0, stream>>>(R, 128, Ab, 256, N);
    // 5. layer 2
    k_gemm<<<dim3(M_pad / 128, Np2 / 128), dim3(256), 0, stream>>>(Ab, 256, Wb1, Kp2, b1, R, 256, Kp2, o2);
    k_ep<256><<<dim3(N), dim3(64), 0, stream>>>(R, 256, Ab, 256, N);
    // 6. layer 3: GEMM -> Y stays in R; epilogue reduced to per-row coefficient
    k_gemm<<<dim3(M_pad / 128, Np3 / 128), dim3(256), 0, stream>>>(Ab, 256, Wb2, Kp3, b2, R, 384, Kp3, o3);
    k_coef<<<dim3(N), dim3(64), 0, stream>>>(R, 384, coefb, N);
    // 7. deterministic mean of ht = C * relu(Y), fused into stage-1
    int NBLK = 2048;
    int chunk = (N + NBLK - 1) / NBLK;
    k_mean<<<dim3(NBLK), dim3(192), 0, stream>>>(R, coefb, partials, N, chunk);
    k_mred<<<dim3(383), dim3(256), 0, stream>>>(partials, hmbuf, NBLK, N);
    // 8. classifier head
    k_head<<<dim3(1), dim3(64), 0, stream>>>(hmbuf, Wc, bc, dout, ic, oc);
}

// Round 13
// 285.013 us; speedup vs baseline: 1.1661x; 1.1240x over previous
//
#include <hip/hip_runtime.h>
#include <math.h>

#define EPSF 1e-7f

typedef unsigned short ushort_t;
typedef __attribute__((ext_vector_type(8))) short bf16x8;
typedef __attribute__((ext_vector_type(4))) float f32x4;

// fast hardware transcendentals (v_exp_f32 / v_log_f32), ~2-4 ulp
__device__ __forceinline__ float fexp(float x) { return __expf(x); }
__device__ __forceinline__ float fsinh(float x) { return 0.5f * (__expf(x) - __expf(-x)); }
__device__ __forceinline__ float arcosh_f(float x) {
    x = fmaxf(x, 1.0f + EPSF);
    return __logf(x + sqrtf(x * x - 1.0f));
}

__device__ __forceinline__ unsigned short f2bf(float f) {
    union { float f; unsigned u; } c; c.f = f;
    unsigned r = c.u + 0x7FFFu + ((c.u >> 16) & 1u);
    return (unsigned short)(r >> 16);
}
__device__ __forceinline__ float bf2f(unsigned short u) {
    union { unsigned u; float f; } c; c.u = ((unsigned)u) << 16;
    return c.f;
}

__device__ __forceinline__ float wredsum(float v) {
#pragma unroll
    for (int off = 32; off; off >>= 1) v += __shfl_xor(v, off, 64);
    return v;
}

__device__ __forceinline__ void llds16(const void* g, void* l) {
    __builtin_amdgcn_global_load_lds((const __attribute__((address_space(1))) unsigned int*)g,
                                     (__attribute__((address_space(3))) unsigned int*)l,
                                     16, 0, 0);
}

// ---------- K1: xt0 = log_map_zero(x) -> bf16, upper half of Abuf rows ----------
__global__ __launch_bounds__(64) void k_log0(const float* __restrict__ x,
                                             char* __restrict__ Abase, int N) {
    int i = blockIdx.x, t = threadIdx.x;
    float2 v = *reinterpret_cast<const float2*>(x + (size_t)i * 128 + 2 * t);
    float y0 = __shfl(v.x, 0, 64);
    float a0 = (t == 0) ? 0.f : v.x;
    float s = wredsum(a0 * a0 + v.y * v.y);
    float dist = arcosh_f(y0 + EPSF);
    float scl = dist / sqrtf(s + EPSF);
    ushort2 o;
    o.x = f2bf(scl * a0);
    o.y = f2bf(scl * v.y);
    *reinterpret_cast<ushort2*>(Abase + (size_t)i * 512 + 256 + 4 * t) = o;
}

// ---------- bucket partition: 1024-node buckets ----------
__global__ __launch_bounds__(256) void k_c1(const int* __restrict__ edst,
                                            int* __restrict__ gcnt,
                                            int E, int NBKT, int EPB) {
    __shared__ int cnt[64];
    int blk = blockIdx.x, t = threadIdx.x;
    for (int i = t; i < NBKT; i += 256) cnt[i] = 0;
    __syncthreads();
    int lo = blk * EPB, hi = min(lo + EPB, E);
    for (int e = lo + t; e < hi; e += 256) atomicAdd(&cnt[edst[e] >> 10], 1);
    __syncthreads();
    for (int i = t; i < NBKT; i += 256) gcnt[blk * NBKT + i] = cnt[i];
}

__global__ __launch_bounds__(64) void k_c2(int* __restrict__ gcnt,
                                           int* __restrict__ bstart, int NBLK, int NBKT) {
    __shared__ int sh[10816];
    __shared__ int tot[64];
    __shared__ int bs[65];
    int t = threadIdx.x;
    int total = NBLK * NBKT;
    for (int i = t; i < total; i += 64) sh[i] = gcnt[i];
    __syncthreads();
    if (t < NBKT) {
        int run = 0;
        for (int blk = 0; blk < NBLK; ++blk) {
            int idx = blk * NBKT + t;
            int c = sh[idx]; sh[idx] = run; run += c;
        }
        tot[t] = run;
    }
    __syncthreads();
    if (t == 0) {
        int r = 0;
        for (int b = 0; b < NBKT; ++b) { bs[b] = r; r += tot[b]; }
        bs[NBKT] = r;
    }
    __syncthreads();
    if (t < NBKT) {
        bstart[t] = bs[t];
        if (t == 0) bstart[NBKT] = bs[NBKT];
    }
    for (int i = t; i < total; i += 64) gcnt[i] = sh[i] + bs[i % NBKT];
}

__global__ __launch_bounds__(256) void k_c3(const int* __restrict__ esrc,
                                            const int* __restrict__ edst,
                                            const int* __restrict__ gcnt,
                                            int2* __restrict__ ebuf,
                                            int E, int NBKT, int EPB) {
    __shared__ int cur[64];
    int blk = blockIdx.x, t = threadIdx.x;
    for (int i = t; i < NBKT; i += 256) cur[i] = 0;
    __syncthreads();
    int lo = blk * EPB, hi = min(lo + EPB, E);
    for (int e = lo + t; e < hi; e += 256) {
        int d = edst[e], s = esrc[e];
        int b = d >> 10;
        int r = atomicAdd(&cur[b], 1);
        ebuf[gcnt[blk * NBKT + b] + r] = make_int2(s, d);
    }
}

// ---------- c4: per-bucket exact CSR (L2-resident scatter) ----------
__global__ __launch_bounds__(256) void k_c4(const int2* __restrict__ ebuf,
                                            const int* __restrict__ bstart,
                                            int* __restrict__ row_ptr,
                                            int* __restrict__ srcl,
                                            int N, int NBKT, int E) {
    __shared__ int cnt[1024];
    __shared__ int cur[1024];
    __shared__ int sb[256];
    int b = blockIdx.x, t = threadIdx.x;
    int lo = b << 10;
    int nn = min(1024, N - lo);
    for (int i = t; i < 1024; i += 256) cnt[i] = 0;
    __syncthreads();
    int es = bstart[b], ee = bstart[b + 1];
    for (int e = es + t; e < ee; e += 256) atomicAdd(&cnt[ebuf[e].y - lo], 1);
    __syncthreads();
    int base = t * 4;
    int c0 = cnt[base], c1 = cnt[base + 1], c2 = cnt[base + 2], c3 = cnt[base + 3];
    int ts = c0 + c1 + c2 + c3;
    sb[t] = ts; __syncthreads();
    for (int st = 1; st < 256; st <<= 1) {
        int v = (t >= st) ? sb[t - st] : 0;
        __syncthreads();
        sb[t] += v;
        __syncthreads();
    }
    int run = es + sb[t] - ts;
    int rp[4];
    rp[0] = run; rp[1] = run + c0; rp[2] = rp[1] + c1; rp[3] = rp[2] + c2;
#pragma unroll
    for (int q = 0; q < 4; ++q) {
        cur[base + q] = rp[q];
        if (base + q < nn) row_ptr[lo + base + q] = rp[q];
    }
    if (b == NBKT - 1 && t == 0) row_ptr[N] = E;
    __syncthreads();
    for (int e = es + t; e < ee; e += 256) {
        int2 ed = ebuf[e];
        int r = atomicAdd(&cur[ed.y - lo], 1);
        srcl[r] = ed.x;
    }
}

// ---------- K3: agg (8-way unrolled gather) + radial-collapsed epilogue ----------
__global__ __launch_bounds__(64) void k_agg(const char* __restrict__ Abase,
                                            const int* __restrict__ row_ptr,
                                            const int* __restrict__ srcl,
                                            ushort_t* __restrict__ Ab, int N) {
    int i = blockIdx.x, t = threadIdx.x;
    const char* base = Abase + 256 + 4 * t;
    ushort2 sv = *reinterpret_cast<const ushort2*>(base + (size_t)i * 512);
    float p0[8], p1[8];
    p0[0] = bf2f(sv.x); p1[0] = bf2f(sv.y);
#pragma unroll
    for (int q = 1; q < 8; ++q) { p0[q] = 0.f; p1[q] = 0.f; }
    int b = row_ptr[i], e = row_ptr[i + 1];
    int k = b;
    for (; k + 8 <= e; k += 8) {
        int s[8];
#pragma unroll
        for (int q = 0; q < 8; ++q) s[q] = srcl[k + q];
        ushort2 v[8];
#pragma unroll
        for (int q = 0; q < 8; ++q)
            v[q] = *reinterpret_cast<const ushort2*>(base + (size_t)s[q] * 512);
#pragma unroll
        for (int q = 0; q < 8; ++q) { p0[q] += bf2f(v[q].x); p1[q] += bf2f(v[q].y); }
    }
    for (; k < e; ++k) {
        int s = srcl[k];
        ushort2 v = *reinterpret_cast<const ushort2*>(base + (size_t)s * 512);
        p0[0] += bf2f(v.x); p1[0] += bf2f(v.y);
    }
    float u0 = ((p0[0] + p0[1]) + (p0[2] + p0[3])) + ((p0[4] + p0[5]) + (p0[6] + p0[7]));
    float u1 = ((p1[0] + p1[1]) + (p1[2] + p1[3])) + ((p1[4] + p1[5]) + (p1[6] + p1[7]));
    if (t == 0) u0 = 0.f;
    float s1 = wredsum(u0 * u0 + u1 * u1);
    float n = sqrtf(fmaxf(s1 + EPSF, 1e-6f));
    float fac = fsinh(fminf(n, 50.f)) / n;
    float S2 = fac * fac * s1;
    float first = sqrtf(1.f + S2);
    float dist = arcosh_f(first + EPSF);
    float C = dist / sqrtf(S2 + EPSF) * fac;
    ushort2 o;
    o.x = f2bf(C * u0);
    o.y = f2bf(C * u1);
    *reinterpret_cast<ushort2*>(Ab + (size_t)i * 256 + 2 * t) = o;
}

// ---------- W conversion (all 3 layers, one launch) ----------
__global__ void k_convw3(const float* __restrict__ W0, const float* __restrict__ W1,
                         const float* __restrict__ W2,
                         ushort_t* __restrict__ Wb0, ushort_t* __restrict__ Wb1,
                         ushort_t* __restrict__ Wb2,
                         int o1, int i1, int Kp1, int o2, int i2, int Kp2,
                         int o3, int i3, int Kp3, int t1, int t2, int t3) {
    int idx = blockIdx.x * blockDim.x + threadIdx.x;
    const float* W; ushort_t* Wb; int ncols, K, Kp, shift;
    if (idx < t1) { W = W0; Wb = Wb0; ncols = o1; K = i1; Kp = Kp1; shift = 1; }
    else if (idx < t1 + t2) { idx -= t1; W = W1; Wb = Wb1; ncols = o2; K = i2; Kp = Kp2; shift = 0; }
    else if (idx < t1 + t2 + t3) { idx -= t1 + t2; W = W2; Wb = Wb2; ncols = o3; K = i3; Kp = Kp3; shift = 0; }
    else return;
    int o = idx / Kp, kk = idx - o * Kp;
    int ks = kk - shift;
    float v = 0.f;
    if (o < ncols && ks >= 0 && ks < K) v = W[(size_t)o * K + ks];
    Wb[idx] = f2bf(v);
}

// ---------- MFMA bf16 GEMM: Yb[M x ncols] = A @ W^T + bias, bf16 output ----------
__global__ __launch_bounds__(256) void k_gemm(const ushort_t* __restrict__ Ab, int lda,
                                              const ushort_t* __restrict__ Wb, int ldw,
                                              const float* __restrict__ bias,
                                              ushort_t* __restrict__ Yb, int ldy,
                                              int Kp, int ncols) {
    __shared__ ushort_t As[128 * 32];
    __shared__ ushort_t Bs[128 * 32];
    int tid = threadIdx.x;
    int lane = tid & 63, wv = tid >> 6;
    int bm = blockIdx.x * 128, bn = blockIdx.y * 128;
    int r = lane & 15, g4 = lane >> 4;
    int wr = (wv >> 1) * 64, wc = (wv & 1) * 64;

    f32x4 acc[4][4] = {};
    for (int k0 = 0; k0 < Kp; k0 += 32) {
#pragma unroll
        for (int ci = 0; ci < 2; ++ci) {
            int L = (wv * 2 + ci) * 1024 + lane * 16;
            int row = L >> 6, kb = L & 63;
            const char* ga = (const char*)Ab + ((size_t)(bm + row) * lda + k0) * 2 + kb;
            llds16(ga, (char*)As + (wv * 2 + ci) * 1024);
            const char* gb = (const char*)Wb + ((size_t)(bn + row) * ldw + k0) * 2 + kb;
            llds16(gb, (char*)Bs + (wv * 2 + ci) * 1024);
        }
        __syncthreads();
        bf16x8 af[4], bfr[4];
#pragma unroll
        for (int m = 0; m < 4; ++m)
            af[m] = *reinterpret_cast<const bf16x8*>((const char*)As + (wr + m * 16 + r) * 64 + g4 * 16);
#pragma unroll
        for (int n2 = 0; n2 < 4; ++n2)
            bfr[n2] = *reinterpret_cast<const bf16x8*>((const char*)Bs + (wc + n2 * 16 + r) * 64 + g4 * 16);
#pragma unroll
        for (int m = 0; m < 4; ++m)
#pragma unroll
            for (int n2 = 0; n2 < 4; ++n2)
                acc[m][n2] = __builtin_amdgcn_mfma_f32_16x16x32_bf16(af[m], bfr[n2], acc[m][n2], 0, 0, 0);
        __syncthreads();
    }
#pragma unroll
    for (int n2 = 0; n2 < 4; ++n2) {
        int col = bn + wc + n2 * 16 + r;
        if (col >= ncols) continue;
        float bv = bias[col];
#pragma unroll
        for (int m = 0; m < 4; ++m) {
#pragma unroll
            for (int j = 0; j < 4; ++j) {
                int row = bm + wr + m * 16 + g4 * 4 + j;
                Yb[(size_t)row * ldy + col] = f2bf(acc[m][n2][j] + bv);
            }
        }
    }
}

// ---------- Epilogue: radial-collapsed chain, 1 row per 64-thread block ----------
template <int NCP>
__global__ __launch_bounds__(64) void k_ep(const ushort_t* __restrict__ Y, int ldy,
                                           ushort_t* __restrict__ out, int ldo, int N) {
    constexpr int CH = NCP / 128;
    int i = blockIdx.x, t = threadIdx.x;
    const ushort_t* yr = Y + (size_t)i * ldy;
    float y[2 * CH], ym[2 * CH];
#pragma unroll
    for (int c = 0; c < CH; ++c) {
        ushort2 v = *reinterpret_cast<const ushort2*>(yr + c * 128 + 2 * t);
        y[2 * c] = bf2f(v.x);
        y[2 * c + 1] = bf2f(v.y);
    }
    if (t == 63) y[2 * CH - 1] = 0.f;  // pad column
    float s1l = 0.f, spl = 0.f;
#pragma unroll
    for (int q = 0; q < 2 * CH; ++q) {
        s1l += y[q] * y[q];
        ym[q] = fmaxf(y[q], 0.f);
        spl += ym[q] * ym[q];
    }
#pragma unroll
    for (int off = 32; off; off >>= 1) {
        s1l += __shfl_xor(s1l, off, 64);
        spl += __shfl_xor(spl, off, 64);
    }
    float s1 = s1l, sp = spl;
    bool allz = (s1 == 0.0f);
    float n1 = sqrtf(fmaxf(s1 + EPSF, 1e-6f));
    float fac1 = fsinh(fminf(n1, 50.f)) / n1;
    float S2 = allz ? 0.f : fac1 * fac1 * s1;
    float first1 = allz ? 0.f : sqrtf(1.f + S2);
    float dist = arcosh_f(first1 + EPSF);
    float rs = dist / sqrtf(S2 + EPSF);
    float coef1 = allz ? 0.f : rs * fac1;
    float S3 = coef1 * coef1 * sp;
    float n2 = sqrtf(fmaxf(S3 + EPSF, 1e-6f));
    float fac2 = fsinh(fminf(n2, 50.f)) / n2;
    float S4 = fac2 * fac2 * S3;
    float first2 = sqrtf(1.f + S4);
    float dist2 = arcosh_f(first2 + EPSF);
    float C = dist2 / sqrtf(S4 + EPSF) * fac2 * coef1;
    ushort_t* orow = out + (size_t)i * ldo;
#pragma unroll
    for (int c = 0; c < CH; ++c) {
        ushort2 o;
        o.x = f2bf(C * ym[2 * c]);
        o.y = f2bf(C * ym[2 * c + 1]);
        *reinterpret_cast<ushort2*>(orow + c * 128 + 2 * t) = o;
    }
}

// ---------- k_coef: layer-3 epilogue coefficient only (no ht write) ----------
__global__ __launch_bounds__(64) void k_coef(const ushort_t* __restrict__ Y, int ldy,
                                             float* __restrict__ coef, int N) {
    constexpr int CH = 3;
    int i = blockIdx.x, t = threadIdx.x;
    const ushort_t* yr = Y + (size_t)i * ldy;
    float y[2 * CH];
#pragma unroll
    for (int c = 0; c < CH; ++c) {
        ushort2 v = *reinterpret_cast<const ushort2*>(yr + c * 128 + 2 * t);
        y[2 * c] = bf2f(v.x);
        y[2 * c + 1] = bf2f(v.y);
    }
    if (t == 63) y[2 * CH - 1] = 0.f;  // pad column 383
    float s1l = 0.f, spl = 0.f;
#pragma unroll
    for (int q = 0; q < 2 * CH; ++q) {
        s1l += y[q] * y[q];
        float m = fmaxf(y[q], 0.f);
        spl += m * m;
    }
#pragma unroll
    for (int off = 32; off; off >>= 1) {
        s1l += __shfl_xor(s1l, off, 64);
        spl += __shfl_xor(spl, off, 64);
    }
    float s1 = s1l, sp = spl;
    bool allz = (s1 == 0.0f);
    float n1 = sqrtf(fmaxf(s1 + EPSF, 1e-6f));
    float fac1 = fsinh(fminf(n1, 50.f)) / n1;
    float S2 = allz ? 0.f : fac1 * fac1 * s1;
    float first1 = allz ? 0.f : sqrtf(1.f + S2);
    float dist = arcosh_f(first1 + EPSF);
    float rs = dist / sqrtf(S2 + EPSF);
    float coef1 = allz ? 0.f : rs * fac1;
    float S3 = coef1 * coef1 * sp;
    float n2 = sqrtf(fmaxf(S3 + EPSF, 1e-6f));
    float fac2 = fsinh(fminf(n2, 50.f)) / n2;
    float S4 = fac2 * fac2 * S3;
    float first2 = sqrtf(1.f + S4);
    float dist2 = arcosh_f(first2 + EPSF);
    float C = dist2 / sqrtf(S4 + EPSF) * fac2 * coef1;
    if (t == 0) coef[i] = C;
}

// ---------- mean partials: reads Y + coef, accumulates C*relu(y). deterministic ----------
__global__ __launch_bounds__(192) void k_mean(const ushort_t* __restrict__ Y,
                                              const float* __restrict__ coef,
                                              float* __restrict__ partials, int N, int chunk) {
    int b = blockIdx.x;
    int t = threadIdx.x;
    int lo = b * chunk;
    int hi = lo + chunk; if (hi > N) hi = N;
    bool lastpair = (t == 191);     // col 383 is pad (garbage) -> exclude
    float a0 = 0.f, a1 = 0.f;
    const ushort_t* p = Y + (size_t)lo * 384 + 2 * t;
    for (int n = lo; n < hi; ++n, p += 384) {
        float c = coef[n];
        ushort2 v = *reinterpret_cast<const ushort2*>(p);
        a0 += c * fmaxf(bf2f(v.x), 0.f);
        if (!lastpair) a1 += c * fmaxf(bf2f(v.y), 0.f);
    }
    float* orow = partials + (size_t)b * 384;
    orow[2 * t] = a0;
    orow[2 * t + 1] = a1;
}

// ---------- stage-2 mean reduce ----------
__global__ __launch_bounds__(256) void k_mred(const float* __restrict__ partials,
                                              float* __restrict__ hm, int nparts, int N) {
    __shared__ float sb[256];
    int j = blockIdx.x, t = threadIdx.x;
    float v = 0.f;
    for (int p = t; p < nparts; p += 256) v += partials[(size_t)p * 384 + j];
    sb[t] = v; __syncthreads();
    for (int st = 128; st > 0; st >>= 1) { if (t < st) sb[t] += sb[t + st]; __syncthreads(); }
    if (t == 0) hm[j] = sb[0] / (float)N;
}

// ---------- classifier head (libm precision retained; negligible cost) ----------
__global__ __launch_bounds__(64) void k_head(const float* __restrict__ hm,
                                             const float* __restrict__ Wc,
                                             const float* __restrict__ bc,
                                             float* __restrict__ dout, int ic, int oc) {
    int t = threadIdx.x;
    float h[6];
    float ss = 0.f;
#pragma unroll
    for (int c = 0; c < 6; ++c) {
        int j = t + 64 * c;
        h[c] = (j < ic) ? hm[j] : 0.f;
        ss += h[c] * h[c];
    }
    float ssum = wredsum(ss);
    float dist = logf(1.0f + EPSF + sqrtf((1.0f + EPSF) * (1.0f + EPSF) - 1.0f));
    float scl = dist / sqrtf(ssum + EPSF);
    float mxv[9];
#pragma unroll
    for (int o = 0; o < 9; ++o) {
        float p = 0.f;
        if (o < oc) {
#pragma unroll
            for (int c = 0; c < 6; ++c) {
                int j = t + 64 * c;
                if (j < ic) p += h[c] * Wc[(size_t)o * ic + j];
            }
        }
        float s = wredsum(p);
        mxv[o] = (o < oc) ? (scl * s + bc[o]) : 0.f;
    }
    if (t == 0) {
        float y[10], tt[10], lt[11], p[11], t3[11];
        float s1 = 0.f, sab = 0.f;
        for (int j = 0; j < 9; ++j) {
            y[j] = (j < oc) ? mxv[j] : 0.f;
            s1 += y[j] * y[j]; sab += fabsf(y[j]);
        }
        bool allz = (sab == 0.f);
        float n = sqrtf(fmaxf(s1 + EPSF, 1e-6f));
        float sh = sinhf(fminf(n, 50.f));
        float s2 = 0.f;
        for (int j = 0; j < oc; ++j) { tt[j] = allz ? 0.f : sh * y[j] / n; s2 += tt[j] * tt[j]; }
        float first = allz ? 0.f : sqrtf(1.f + s2);
        dout[0] = first;
        for (int j = 0; j < oc; ++j) dout[1 + j] = tt[j];
        float xx = fmaxf(first + EPSF, 1.0f + EPSF);
        float dist2 = logf(xx + sqrtf(xx * xx - 1.0f));
        float nrm2 = sqrtf(s2 + EPSF);
        lt[0] = 0.f;
        for (int j = 0; j < oc; ++j) lt[1 + j] = dist2 / nrm2 * tt[j];
        float m = lt[0];
        for (int j = 1; j <= oc; ++j) m = fmaxf(m, lt[j]);
        float es = 0.f;
        for (int j = 0; j <= oc; ++j) { p[j] = expf(lt[j] - m); es += p[j]; }
        for (int j = 0; j <= oc; ++j) p[j] /= es;
        p[0] = 0.f;
        float s3 = 0.f;
        for (int j = 1; j <= oc; ++j) s3 += p[j] * p[j];
        float n3 = sqrtf(fmaxf(s3 + EPSF, 1e-6f));
        float sh3 = sinhf(fminf(n3, 50.f));
        float s4 = 0.f;
        for (int j = 1; j <= oc; ++j) { t3[j] = sh3 * p[j] / n3; s4 += t3[j] * t3[j]; }
        dout[1 + oc] = sqrtf(1.f + s4);
        for (int j = 1; j <= oc; ++j) dout[1 + oc + j] = t3[j];
    }
}

extern "C" void kernel_launch(void* const* d_in, const int* in_sizes, int n_in,
                              void* d_out, int out_size, void* d_ws, size_t ws_size,
                              hipStream_t stream) {
    if (n_in < 10) return;
    const float* x   = (const float*)d_in[0];
    const int*   ei  = (const int*)d_in[1];
    const float* W0  = (const float*)d_in[2];
    const float* b0  = (const float*)d_in[3];
    const float* W1  = (const float*)d_in[4];
    const float* b1  = (const float*)d_in[5];
    const float* W2  = (const float*)d_in[6];
    const float* b2  = (const float*)d_in[7];
    const float* Wc  = (const float*)d_in[8];
    const float* bc  = (const float*)d_in[9];
    float* dout = (float*)d_out;

    int N = in_sizes[0] / 128;
    int E = in_sizes[1] / 2;
    int o1 = in_sizes[3];
    int i1 = in_sizes[2] / o1;
    int o2 = in_sizes[5];
    int i2 = in_sizes[4] / o2;
    int o3 = in_sizes[7];
    int i3 = in_sizes[6] / o3;
    int oc = in_sizes[9];
    int ic = in_sizes[8] / oc;

    int M_pad = ((N + 127) / 128) * 128;
    int Kp1 = ((i1 + 31) / 32) * 32;
    int Kp2 = ((i2 + 31) / 32) * 32;
    int Kp3 = ((i3 + 31) / 32) * 32;
    int Np1 = ((o1 + 127) / 128) * 128;
    int Np2 = ((o2 + 127) / 128) * 128;
    int Np3 = ((o3 + 127) / 128) * 128;

    const int* esrc = ei;
    const int* edst = ei + E;

    char* ws = (char*)d_ws;
    auto alloc = [&](size_t bytes) {
        char* p = ws;
        ws += (bytes + 511) & ~(size_t)511;
        return p;
    };
    ushort_t* Ab     = (ushort_t*)alloc((size_t)M_pad * 256 * 2);
    ushort_t* R      = (ushort_t*)alloc((size_t)M_pad * 384 * 2);
    ushort_t* Wb0    = (ushort_t*)alloc((size_t)Np1 * Kp1 * 2);
    ushort_t* Wb1    = (ushort_t*)alloc((size_t)Np2 * Kp2 * 2);
    ushort_t* Wb2    = (ushort_t*)alloc((size_t)Np3 * Kp3 * 2);
    int2*     ebuf   = (int2*)alloc((size_t)E * 8);
    int*      gcnt   = (int*)alloc((size_t)256 * 64 * 4);
    int*      bstart = (int*)alloc(128 * 4);
    int*      row_ptr= (int*)alloc((size_t)(N + 1) * 4);
    int*      srcl   = (int*)alloc((size_t)E * 4);
    float*    coefb  = (float*)alloc((size_t)N * 4);
    float*    partials = (float*)alloc((size_t)2048 * 384 * 4);
    float*    hmbuf  = (float*)alloc(512 * 4);
    (void)ws_size;

    int NBKT = (N + 1023) >> 10;
    int EPB = 4096;
    int NBLK_E = (E + EPB - 1) / EPB;

    int t1 = Np1 * Kp1, t2 = Np2 * Kp2, t3 = Np3 * Kp3;
    k_convw3<<<dim3((t1 + t2 + t3 + 255) / 256), dim3(256), 0, stream>>>(
        W0, W1, W2, Wb0, Wb1, Wb2, o1, i1, Kp1, o2, i2, Kp2, o3, i3, Kp3, t1, t2, t3);
    // 1. log_map_zero(x) -> xt0 bf16
    k_log0<<<dim3(N), dim3(64), 0, stream>>>(x, (char*)Ab, N);
    // 2. bucket partition + per-bucket exact CSR
    k_c1<<<dim3(NBLK_E), dim3(256), 0, stream>>>(edst, gcnt, E, NBKT, EPB);
    k_c2<<<dim3(1), dim3(64), 0, stream>>>(gcnt, bstart, NBLK_E, NBKT);
    k_c3<<<dim3(NBLK_E), dim3(256), 0, stream>>>(esrc, edst, gcnt, ebuf, E, NBKT, EPB);
    k_c4<<<dim3(NBKT), dim3(256), 0, stream>>>(ebuf, bstart, row_ptr, srcl, N, NBKT, E);
    // 3. aggregate (8-way MLP gather) + collapsed epilogue -> A (bf16)
    k_agg<<<dim3(N), dim3(64), 0, stream>>>((const char*)Ab, row_ptr, srcl, Ab, N);
    // 4. layer 1
    k_gemm<<<dim3(M_pad / 128, Np1 / 128), dim3(256), 0, stream>>>(Ab, 256, Wb0, Kp1, b0, R, 128, Kp1, o1);
    k_ep<128><<<dim3(N), dim3(64), 0, stream>>>(R, 128, Ab, 256, N);
    // 5. layer 2
    k_gemm<<<dim3(M_pad / 128, Np2 / 128), dim3(256), 0, stream>>>(Ab, 256, Wb1, Kp2, b1, R, 256, Kp2, o2);
    k_ep<256><<<dim3(N), dim3(64), 0, stream>>>(R, 256, Ab, 256, N);
    // 6. layer 3: GEMM -> Y stays in R; epilogue reduced to per-row coefficient
    k_gemm<<<dim3(M_pad / 128, Np3 / 128), dim3(256), 0, stream>>>(Ab, 256, Wb2, Kp3, b2, R, 384, Kp3, o3);
    k_coef<<<dim3(N), dim3(64), 0, stream>>>(R, 384, coefb, N);
    // 7. deterministic mean of ht = C * relu(Y), fused into stage-1
    int NBLK = 2048;
    int chunk = (N + NBLK - 1) / NBLK;
    k_mean<<<dim3(NBLK), dim3(192), 0, stream>>>(R, coefb, partials, N, chunk);
    k_mred<<<dim3(383), dim3(256), 0, stream>>>(partials, hmbuf, NBLK, N);
    // 8. classifier head
    k_head<<<dim3(1), dim3(64), 0, stream>>>(hmbuf, Wc, bc, dout, ic, oc);
}